// Round 14
// baseline (864.561 us; speedup 1.0000x reference)
//
#include <hip/hip_runtime.h>
#include <hip/hip_bf16.h>
#include <math.h>

typedef __hip_bfloat16 bf16;
typedef __attribute__((ext_vector_type(8))) short short8;
typedef __attribute__((ext_vector_type(4))) short short4v;
typedef __attribute__((ext_vector_type(4))) float f32x4;

__device__ __forceinline__ void storef(float* p, float v){ *p = v; }
__device__ __forceinline__ void storef(bf16* p, float v){ *p = __float2bfloat16(v); }
__device__ __forceinline__ float sigm(float x){ return 1.0f/(1.0f+expf(-x)); }
__device__ __forceinline__ float tof(float x){ return x; }
__device__ __forceinline__ float tof(bf16 x){ return __bfloat162float(x); }

__device__ __forceinline__ short f2bs(float f){ bf16 h=__float2bfloat16(f); short s; __builtin_memcpy(&s,&h,2); return s; }
__device__ __forceinline__ void load8(const float* __restrict__ p, short8* dst){
    const f32x4* pp = (const f32x4*)p;
    f32x4 lo = pp[0], hi = pp[1];
    short8 v;
    v[0]=f2bs(lo[0]); v[1]=f2bs(lo[1]); v[2]=f2bs(lo[2]); v[3]=f2bs(lo[3]);
    v[4]=f2bs(hi[0]); v[5]=f2bs(hi[1]); v[6]=f2bs(hi[2]); v[7]=f2bs(hi[3]);
    *dst = v;
}
__device__ __forceinline__ void load8(const bf16* __restrict__ p, short8* dst){
    *dst = *(const short8*)p;
}

__device__ __forceinline__ void gl_lds16(const bf16* g, bf16* l){
    auto gp = (const __attribute__((address_space(1))) unsigned int*)(g);
    auto lp = (__attribute__((address_space(3))) unsigned int*)(l);
    __builtin_amdgcn_global_load_lds(gp, lp, 16, 0, 0);
}

// ============ fast bf16 GEMM: C[M,N] = A[M,K] @ B[N,K]^T + bias ============
// WSEQ>0: cols >= WCUT get the transposed write to C2:
//   C2[((row/WSEQ)*8 + colv/64)*64 + colv%64][row%WSEQ], colv = col-WCUT, ld = WLDT.
template<int TM, int TN, typename OT, bool RELU, int WSEQ = 0, int WLDT = 0, int WCUT = 0>
__global__ __launch_bounds__(256) void k_gemm_fast(
    const bf16* __restrict__ A, int lda,
    const bf16* __restrict__ B, int ldb,
    OT* __restrict__ C, int ldc, bf16* __restrict__ C2,
    const float* __restrict__ bias, int K)
{
    constexpr int FM = TM/32, FN = TN/32;
    __shared__ bf16 As[TM*32];
    __shared__ bf16 Bs[TN*32];
    const int tid = threadIdx.x;
    const int wave = tid >> 6, lane = tid & 63;
    const int m0 = blockIdx.y * TM, n0 = blockIdx.x * TN;
    const int wm = (wave >> 1) * (TM/2), wn = (wave & 1) * (TN/2);
    const int lr = lane & 15, g = lane >> 4;
    const int srow = lane >> 2, sslot = (lane & 3) * 8;
    f32x4 acc[FM][FN] = {};

    for (int k0 = 0; k0 < K; k0 += 32) {
        #pragma unroll
        for (int rd = 0; rd < TM/64; ++rd) {
            int cb = rd*4 + wave;
            gl_lds16(A + (size_t)(m0 + cb*16 + srow)*lda + k0 + sslot, As + cb*512);
        }
        #pragma unroll
        for (int rd = 0; rd < TN/64; ++rd) {
            int cb = rd*4 + wave;
            gl_lds16(B + (size_t)(n0 + cb*16 + srow)*ldb + k0 + sslot, Bs + cb*512);
        }
        __syncthreads();
        short8 af[FM], bf_[FN];
        #pragma unroll
        for (int i = 0; i < FM; ++i) af[i]  = *(const short8*)&As[(wm + i*16 + lr)*32 + g*8];
        #pragma unroll
        for (int j = 0; j < FN; ++j) bf_[j] = *(const short8*)&Bs[(wn + j*16 + lr)*32 + g*8];
        #pragma unroll
        for (int i = 0; i < FM; ++i)
            #pragma unroll
            for (int j = 0; j < FN; ++j)
                acc[i][j] = __builtin_amdgcn_mfma_f32_16x16x32_bf16(af[i], bf_[j], acc[i][j], 0, 0, 0);
        __syncthreads();
    }
    const int cr4 = (lane >> 4) * 4;
    #pragma unroll
    for (int j = 0; j < FN; ++j) {
        int col = n0 + wn + j*16 + lr;
        float bv = bias[col];
        if (WSEQ > 0 && col >= WCUT) {
            int colv = col - WCUT;
            int hh = colv >> 6, dd = colv & 63;
            #pragma unroll
            for (int i = 0; i < FM; ++i) {
                int r0 = m0 + wm + i*16 + cr4;
                int bb = r0 / WSEQ, ll = r0 % WSEQ;
                short4v pk;
                #pragma unroll
                for (int q = 0; q < 4; ++q) pk[q] = f2bs(acc[i][j][q] + bv);
                *(short4v*)&C2[((size_t)(bb*8 + hh)*64 + dd)*WLDT + ll] = pk;
            }
        } else {
            #pragma unroll
            for (int i = 0; i < FM; ++i) {
                #pragma unroll
                for (int q = 0; q < 4; ++q) {
                    int row = m0 + wm + i*16 + cr4 + q;
                    float v = acc[i][j][q] + bv;
                    if (RELU) v = fmaxf(v, 0.0f);
                    storef(&C[(size_t)row*ldc + col], v);
                }
            }
        }
    }
}

// ============ fused attention ============
// VT=true: V is V^T [(b*8+h)*64+d][LKT] (padded cols >= LK are zero); PV reads global.
// CAUSAL: skip K-chunks / PV-chunks that are fully masked for this q-tile (outputs identical:
// acc stays 0 there and those cols are -INF-masked for every row of the tile; Ps still gets
// exact 0s and the full Pout dump is preserved).
template<int LK, int LKT, bool CAUSAL, bool WPROB, bool VT>
__global__ __launch_bounds__(256) void k_attn(
    const bf16* __restrict__ Q, int ldq, const bf16* __restrict__ K, int ldk,
    const bf16* __restrict__ V, int ldv,
    float* __restrict__ Pout, bf16* __restrict__ ctx)
{
    constexpr int LQ = 512;
    constexpr int NCH = (LK + 63) / 64;
    constexpr int LKP = NCH*64 + 8;
    __shared__ bf16 Qs[32*72];
    __shared__ bf16 Ks[64*72];
    __shared__ bf16 Ps[32*LKP];
    __shared__ float red[4][32];
    const int tid = threadIdx.x, wave = tid >> 6, lane = tid & 63;
    const int lr = lane & 15, g = lane >> 4;
    const int qt = blockIdx.x, bh = blockIdx.y;
    const int b = bh >> 3, h = bh & 7;
    const size_t qbase = (size_t)b*LQ + qt*32;
    const size_t kvbase = (size_t)b*LK;
    const int nch = CAUSAL ? ((qt >> 1) + 1) : NCH;          // active 64-col chunks
    {
        int r = tid >> 3, c = (tid & 7) << 3;
        *(short8*)&Qs[r*72 + c] = *(const short8*)&Q[(qbase + r)*ldq + h*64 + c];
    }
    f32x4 acc[2][NCH];
    #pragma unroll
    for (int i = 0; i < 2; ++i)
        #pragma unroll
        for (int j = 0; j < NCH; ++j) acc[i][j] = (f32x4){0,0,0,0};

    for (int ch = 0; ch < nch; ++ch) {
        __syncthreads();
        #pragma unroll
        for (int i = 0; i < 2; ++i) {
            int idx = tid + i*256;
            int r = idx >> 3, c = (idx & 7) << 3;
            int kr = ch*64 + r;
            short8 v = {};
            if (kr < LK) v = *(const short8*)&K[(kvbase + kr)*ldk + h*64 + c];
            *(short8*)&Ks[r*72 + c] = v;
        }
        __syncthreads();
        #pragma unroll
        for (int kk = 0; kk < 2; ++kk) {
            short8 bf_ = *(const short8*)&Ks[(wave*16 + lr)*72 + kk*32 + g*8];
            #pragma unroll
            for (int mi = 0; mi < 2; ++mi) {
                short8 af = *(const short8*)&Qs[(mi*16 + lr)*72 + kk*32 + g*8];
                acc[mi][ch] = __builtin_amdgcn_mfma_f32_16x16x32_bf16(af, bf_, acc[mi][ch], 0, 0, 0);
            }
        }
    }
    __syncthreads();
    // ---- softmax ----
    float rmax[2][4];
    #pragma unroll
    for (int mi = 0; mi < 2; ++mi)
        #pragma unroll
        for (int q = 0; q < 4; ++q) {
            int rowg = qt*32 + mi*16 + g*4 + q;
            float m = -INFINITY;
            #pragma unroll
            for (int ch = 0; ch < NCH; ++ch) {
                int col = ch*64 + wave*16 + lr;
                float s = acc[mi][ch][q] * 0.125f;
                if (col >= LK || (CAUSAL && col > rowg)) s = -INFINITY;
                acc[mi][ch][q] = s;
                m = fmaxf(m, s);
            }
            rmax[mi][q] = m;
        }
    #pragma unroll
    for (int off = 1; off < 16; off <<= 1)
        #pragma unroll
        for (int mi = 0; mi < 2; ++mi)
            #pragma unroll
            for (int q = 0; q < 4; ++q)
                rmax[mi][q] = fmaxf(rmax[mi][q], __shfl_xor(rmax[mi][q], off));
    if (lr == 0)
        #pragma unroll
        for (int mi = 0; mi < 2; ++mi)
            #pragma unroll
            for (int q = 0; q < 4; ++q)
                red[wave][mi*16 + g*4 + q] = rmax[mi][q];
    __syncthreads();
    float rsum[2][4];
    #pragma unroll
    for (int mi = 0; mi < 2; ++mi)
        #pragma unroll
        for (int q = 0; q < 4; ++q) {
            int rl = mi*16 + g*4 + q;
            float m = fmaxf(fmaxf(red[0][rl], red[1][rl]), fmaxf(red[2][rl], red[3][rl]));
            float s = 0.0f;
            #pragma unroll
            for (int ch = 0; ch < NCH; ++ch) {
                float e = expf(acc[mi][ch][q] - m);
                acc[mi][ch][q] = e;
                s += e;
            }
            rsum[mi][q] = s;
        }
    #pragma unroll
    for (int off = 1; off < 16; off <<= 1)
        #pragma unroll
        for (int mi = 0; mi < 2; ++mi)
            #pragma unroll
            for (int q = 0; q < 4; ++q)
                rsum[mi][q] += __shfl_xor(rsum[mi][q], off);
    __syncthreads();
    if (lr == 0)
        #pragma unroll
        for (int mi = 0; mi < 2; ++mi)
            #pragma unroll
            for (int q = 0; q < 4; ++q)
                red[wave][mi*16 + g*4 + q] = rsum[mi][q];
    __syncthreads();
    #pragma unroll
    for (int mi = 0; mi < 2; ++mi)
        #pragma unroll
        for (int q = 0; q < 4; ++q) {
            int rl = mi*16 + g*4 + q;
            float inv = 1.0f / (red[0][rl] + red[1][rl] + red[2][rl] + red[3][rl]);
            #pragma unroll
            for (int ch = 0; ch < NCH; ++ch) {
                int col = ch*64 + wave*16 + lr;
                Ps[rl*LKP + col] = __float2bfloat16(acc[mi][ch][q] * inv);
            }
        }
    __syncthreads();
    // ---- coalesced prob dump (full range; masked cols are exact 0) ----
    if (WPROB) {
        const size_t pbase = ((size_t)bh*LQ + qt*32)*LK;
        constexpr int NV = 32*LK/4;
        for (int p = tid; p < NV; p += 256) {
            int e = p*4;
            int row = e / LK, col = e % LK;
            f32x4 v;
            #pragma unroll
            for (int u = 0; u < 4; ++u) v[u] = tof(Ps[row*LKP + col + u]);
            *(f32x4*)&Pout[pbase + (size_t)row*LK + col] = v;
        }
    }
    // ---- PV ----
    const int pcmax = CAUSAL ? (qt + 1) : 2*NCH;             // active 32-col chunks
    f32x4 o[2] = {(f32x4){0,0,0,0},(f32x4){0,0,0,0}};
    if constexpr (VT) {
        const bf16* vrow = V + ((size_t)(b*8 + h)*64 + wave*16 + lr)*LKT;
        for (int pc = 0; pc < pcmax; ++pc) {
            short8 bf_ = *(const short8*)&vrow[pc*32 + g*8];
            #pragma unroll
            for (int mi = 0; mi < 2; ++mi) {
                short8 af = *(const short8*)&Ps[(mi*16 + lr)*LKP + pc*32 + g*8];
                o[mi] = __builtin_amdgcn_mfma_f32_16x16x32_bf16(af, bf_, o[mi], 0, 0, 0);
            }
        }
    } else {
        short* Vs = (short*)Ks;
        for (int pc = 0; pc < pcmax; ++pc) {
            __syncthreads();
            {
                int r = tid >> 3, c = (tid & 7) << 3;
                int kr = pc*32 + r;
                short8 v = {};
                if (kr < LK) v = *(const short8*)&V[(kvbase + kr)*ldv + h*64 + c];
                #pragma unroll
                for (int j = 0; j < 8; ++j) Vs[(c + j)*40 + r] = v[j];
            }
            __syncthreads();
            short8 bf_ = *(const short8*)&Vs[(wave*16 + lr)*40 + g*8];
            #pragma unroll
            for (int mi = 0; mi < 2; ++mi) {
                short8 af = *(const short8*)&Ps[(mi*16 + lr)*LKP + pc*32 + g*8];
                o[mi] = __builtin_amdgcn_mfma_f32_16x16x32_bf16(af, bf_, o[mi], 0, 0, 0);
            }
        }
    }
    const int cr4g = g * 4;
    #pragma unroll
    for (int mi = 0; mi < 2; ++mi)
        #pragma unroll
        for (int q = 0; q < 4; ++q) {
            int rl = mi*16 + cr4g + q;
            storef(&ctx[(qbase + rl)*512 + h*64 + wave*16 + lr], o[mi][q]);
        }
}

// ---------------- bulk f32 -> bf16 converter
struct CvtSeg { const float* src; bf16* dst; };
struct CvtArgs { CvtSeg seg[16]; int cum[17]; int nseg; };
__global__ void k_cvt(CvtArgs a)
{
    int gid = blockIdx.x*256 + threadIdx.x;
    if (gid >= a.cum[a.nseg]) return;
    int s = 0;
    while (s < a.nseg-1 && gid >= a.cum[s+1]) ++s;
    int off = (gid - a.cum[s]) * 8;
    short8 v; load8(a.seg[s].src + off, &v);
    *(short8*)(a.seg[s].dst + off) = v;
}

// ---------------- attr pad-convert
__global__ void k_cvt_pad(const float* __restrict__ a, const float* __restrict__ wk,
                          const float* __restrict__ wv, bf16* __restrict__ attrp,
                          bf16* __restrict__ kvwp)
{
    int t = blockIdx.x*256 + threadIdx.x;     // 1344*320
    if (t >= 1344*320) return;
    int r = t / 320, c = t % 320;
    float v = 0.0f;
    if (c < 300) {
        if (r < 320) v = a[(size_t)r*300 + c];
        else if (r < 832) v = wk[(size_t)(r-320)*300 + c];
        else v = wv[(size_t)(r-832)*300 + c];
    }
    if (r < 320) storef(&attrp[(size_t)r*320 + c], v);
    else storef(&kvwp[(size_t)(r-320)*320 + c], v);
}

__global__ void k_cat2(const float* __restrict__ a, const float* __restrict__ b,
                       float* __restrict__ dst)
{
    int t = blockIdx.x*256 + threadIdx.x;
    if (t < 512) dst[t] = a[t];
    else if (t < 1024) dst[t] = b[t-512];
}

__global__ void k_cat3(const float* __restrict__ a, const float* __restrict__ b,
                       const float* __restrict__ c, float* __restrict__ dst)
{
    int t = blockIdx.x*256 + threadIdx.x;
    if (t < 512) dst[t] = a[t];
    else if (t < 1024) dst[t] = b[t-512];
    else if (t < 1536) dst[t] = c[t-1024];
}

__global__ void k_zero(bf16* __restrict__ p, int n8)
{
    int t = blockIdx.x*256 + threadIdx.x;
    if (t < n8) { short8 z = {}; *(short8*)&p[t*8] = z; }
}

// ---------------- fused custom-LN + GLU -> bf16 [8192,256]
__global__ void k_lnglu(const float* __restrict__ x, const float* __restrict__ a,
                        const float* __restrict__ bpar, bf16* __restrict__ out)
{
    int r = blockIdx.x, tid = threadIdx.x;
    const float* xr = x + (size_t)r*512;
    float v0 = xr[tid], v1 = xr[tid+256];
    __shared__ float red[256];
    red[tid] = v0+v1; __syncthreads();
    for (int s=128;s>0;s>>=1){ if(tid<s) red[tid]+=red[tid+s]; __syncthreads(); }
    float mean = red[0]*(1.0f/512.0f); __syncthreads();
    float d0 = v0-mean, d1 = v1-mean;
    red[tid] = d0*d0+d1*d1; __syncthreads();
    for (int s=128;s>0;s>>=1){ if(tid<s) red[tid]+=red[tid+s]; __syncthreads(); }
    float stdv = sqrtf(red[0]*(1.0f/511.0f));
    float inv = 1.0f/(stdv + 1e-6f);
    float o0 = a[tid]    *d0*inv + bpar[tid];
    float o1 = a[tid+256]*d1*inv + bpar[tid+256];
    storef(&out[(size_t)r*256 + tid], o0 * sigm(o1));
}

// ---------------- LSTM steps t=0,1
__global__ void k_lstm_step(const bf16* __restrict__ XW, const bf16* __restrict__ G,
                            const float* __restrict__ bih, const float* __restrict__ bhh,
                            bf16* __restrict__ h, float* __restrict__ c, int t, int first)
{
    int idx = blockIdx.x*256 + threadIdx.x;
    int n = idx >> 9, j = idx & 511;
    int b = n >> 9, l = n & 511;
    int lp = l - 2 + t;
    float gi, gf, gg, go;
    if (lp >= 0) {
        const bf16* xr = XW + ((size_t)(b*512 + lp))*2048;
        gi = tof(xr[j]); gf = tof(xr[512+j]); gg = tof(xr[1024+j]); go = tof(xr[1536+j]);
    } else {
        gi = bih[j]; gf = bih[512+j]; gg = bih[1024+j]; go = bih[1536+j];
    }
    if (first) {
        gi += bhh[j]; gf += bhh[512+j]; gg += bhh[1024+j]; go += bhh[1536+j];
        float cn = sigm(gi)*tanhf(gg);
        c[idx] = cn;
        storef(&h[idx], sigm(go)*tanhf(cn));
    } else {
        const bf16* gr = G + (size_t)n*2048;
        gi += tof(gr[j]); gf += tof(gr[512+j]); gg += tof(gr[1024+j]); go += tof(gr[1536+j]);
        float cn = sigm(gf)*c[idx] + sigm(gi)*tanhf(gg);
        c[idx] = cn;
        storef(&h[idx], sigm(go)*tanhf(cn));
    }
}

// ---------------- LSTM final step t=2 fused with residual add: x1 = dec + h
__global__ void k_lstm_last(const bf16* __restrict__ XW, const bf16* __restrict__ G,
                            const float* __restrict__ dec, const float* __restrict__ c,
                            float* __restrict__ x1f, bf16* __restrict__ x1b)
{
    int idx = blockIdx.x*256 + threadIdx.x;
    int n = idx >> 9, j = idx & 511;
    int b = n >> 9, l = n & 511;
    const bf16* xr = XW + ((size_t)(b*512 + l))*2048;
    float gi = tof(xr[j]), gf = tof(xr[512+j]), gg = tof(xr[1024+j]), go = tof(xr[1536+j]);
    const bf16* gr = G + (size_t)n*2048;
    gi += tof(gr[j]); gf += tof(gr[512+j]); gg += tof(gr[1024+j]); go += tof(gr[1536+j]);
    float cn = sigm(gf)*c[idx] + sigm(gi)*tanhf(gg);
    float h = sigm(go)*tanhf(cn);
    float v = dec[idx] + h;
    x1f[idx] = v;
    storef(&x1b[idx], v);
}

template<typename RT>
__global__ void k_ln_res(const bf16* __restrict__ x, const RT* __restrict__ res,
                         float* __restrict__ out, bf16* __restrict__ outb, float eps)
{
    int r = blockIdx.x, tid = threadIdx.x;
    const bf16* xr = x + (size_t)r*512;
    const RT* rr = res + (size_t)r*512;
    float v0 = tof(xr[tid]) + tof(rr[tid]), v1 = tof(xr[tid+256]) + tof(rr[tid+256]);
    __shared__ float red[256];
    red[tid] = v0+v1; __syncthreads();
    for (int s=128;s>0;s>>=1){ if(tid<s) red[tid]+=red[tid+s]; __syncthreads(); }
    float mean = red[0]*(1.0f/512.0f); __syncthreads();
    float d0 = v0-mean, d1 = v1-mean;
    red[tid] = d0*d0+d1*d1; __syncthreads();
    for (int s=128;s>0;s>>=1){ if(tid<s) red[tid]+=red[tid+s]; __syncthreads(); }
    float inv = rsqrtf(red[0]*(1.0f/512.0f) + eps);
    float o0 = d0*inv, o1 = d1*inv;
    out[(size_t)r*512 + tid]     = o0;
    out[(size_t)r*512 + tid+256] = o1;
    if (outb) {
        storef(&outb[(size_t)r*512 + tid],     o0);
        storef(&outb[(size_t)r*512 + tid+256], o1);
    }
}

__global__ void k_gate_ln(const bf16* __restrict__ ctpre, const float* __restrict__ img,
                          const float* __restrict__ attr, const float* __restrict__ na,
                          const float* __restrict__ nb, bf16* __restrict__ out)
{
    int r = blockIdx.x, tid = threadIdx.x;
    size_t base = (size_t)r*512;
    float ct0 = sigm(tof(ctpre[base+tid]));
    float v0 = ct0*fmaxf(img[base+tid],0.f) + (1.f-ct0)*fmaxf(attr[base+tid],0.f);
    float ct1 = sigm(tof(ctpre[base+tid+256]));
    float v1 = ct1*fmaxf(img[base+tid+256],0.f) + (1.f-ct1)*fmaxf(attr[base+tid+256],0.f);
    __shared__ float red[256];
    red[tid] = v0+v1; __syncthreads();
    for (int s=128;s>0;s>>=1){ if(tid<s) red[tid]+=red[tid+s]; __syncthreads(); }
    float mean = red[0]*(1.0f/512.0f); __syncthreads();
    float d0 = v0-mean, d1 = v1-mean;
    red[tid] = d0*d0+d1*d1; __syncthreads();
    for (int s=128;s>0;s>>=1){ if(tid<s) red[tid]+=red[tid+s]; __syncthreads(); }
    float stdv = sqrtf(red[0]*(1.0f/511.0f));
    float inv = 1.0f/(stdv + 1e-6f);
    storef(&out[base+tid],     na[tid]    *d0*inv + nb[tid]);
    storef(&out[base+tid+256], na[tid+256]*d1*inv + nb[tid+256]);
}

__global__ void k_fold(const float* __restrict__ fcw, bf16* __restrict__ fold)
{
    int idx = blockIdx.x*256 + threadIdx.x;
    int d = idx >> 9, j = idx & 511;
    storef(&fold[idx], fcw[(size_t)d*1024 + j] + fcw[(size_t)d*1024 + 512 + j]);
}

extern "C" void kernel_launch(void* const* d_in, const int* in_sizes, int n_in,
                              void* d_out, int out_size, void* d_ws, size_t ws_size,
                              hipStream_t stream)
{
    const float* dec_inputs  = (const float*)d_in[0];
    const float* enc_outputs = (const float*)d_in[1];
    const float* attr_out    = (const float*)d_in[2];
    const float* rnn_a  = (const float*)d_in[6];
    const float* rnn_b  = (const float*)d_in[7];
    const float* conv_w = (const float*)d_in[8];
    const float* conv_b = (const float*)d_in[9];
    const float* w_ih   = (const float*)d_in[10];
    const float* w_hh   = (const float*)d_in[11];
    const float* b_ih   = (const float*)d_in[12];
    const float* b_hh   = (const float*)d_in[13];
    const float* sa_wq  = (const float*)d_in[14]; const float* sa_bq = (const float*)d_in[15];
    const float* sa_wk  = (const float*)d_in[16]; const float* sa_bk = (const float*)d_in[17];
    const float* sa_wv  = (const float*)d_in[18]; const float* sa_bv = (const float*)d_in[19];
    const float* sa_wo  = (const float*)d_in[20]; const float* sa_bo = (const float*)d_in[21];
    const float* ea_wq  = (const float*)d_in[22]; const float* ea_bq = (const float*)d_in[23];
    const float* ea_wk  = (const float*)d_in[24]; const float* ea_bk = (const float*)d_in[25];
    const float* ea_wv  = (const float*)d_in[26]; const float* ea_bv = (const float*)d_in[27];
    const float* ea_wo  = (const float*)d_in[28]; const float* ea_bo = (const float*)d_in[29];
    const float* aa_wq  = (const float*)d_in[30]; const float* aa_bq = (const float*)d_in[31];
    const float* aa_wk  = (const float*)d_in[32]; const float* aa_bk = (const float*)d_in[33];
    const float* aa_wv  = (const float*)d_in[34]; const float* aa_bv = (const float*)d_in[35];
    const float* aa_wo  = (const float*)d_in[36]; const float* aa_bo = (const float*)d_in[37];
    const float* fc_w   = (const float*)d_in[38]; const float* fc_b  = (const float*)d_in[39];
    const float* norm_a = (const float*)d_in[40]; const float* norm_b= (const float*)d_in[41];
    const float* ffn_w1 = (const float*)d_in[42]; const float* ffn_b1= (const float*)d_in[43];
    const float* ffn_w2 = (const float*)d_in[44]; const float* ffn_b2= (const float*)d_in[45];

    float* out_y  = (float*)d_out;
    float* out_sa = out_y + 4194304ull;      // [16,8,512,512] f32
    float* out_ea = out_sa + 33554432ull;    // [16,8,512,196] f32

    // scratch inside out_sa (dead until k_attn<self> writes it)
    bf16* xwb = (bf16*)out_sa;                    // [8192,2048]
    bf16* gb  = xwb + 16777216ull;
    bf16* wA  = (bf16*)(out_sa + 16777216ull);
    bf16* conv_wb = wA;
    bf16* w_ihb   = conv_wb + 131072;
    bf16* w_hhb   = w_ihb + 1048576;
    bf16* sa_wqb  = w_hhb + 1048576;              // wq|wk|wv adjacent (fused QKV)
    bf16* sa_wkb  = sa_wqb + 262144;
    bf16* sa_wvb  = sa_wkb + 262144;
    // scratch inside out_ea (dead until k_attn<enc> writes it)
    bf16* enc_b   = (bf16*)out_ea;                // [3136,4096]
    bf16* ea_wkb  = (bf16*)(out_ea + 6422528ull); // wk|wv adjacent (fused KV)
    bf16* ea_wvb  = ea_wkb + 2097152;

    char* W = (char*)d_ws;
    float* S0 = (float*)(W);                      // x1 / attr ; aliases (dead phases)
    float* S1 = (float*)(W + (16ull<<20));        // dec_out ; midb in E
    float* S2 = (float*)(W + (32ull<<20));        // c / img
    bf16*  T0 = (bf16*) (W + (48ull<<20));        // fat q|k [8192,1024] spans T0..T1 / ctpre
    bf16*  T1 = (bf16*) (W + (56ull<<20));        // proj out / ffn2out
    bf16*  T2 = (bf16*) (W + (64ull<<20));        // vt_self / proj out / y1
    bf16*  T3 = (bf16*) (W + (72ull<<20));        // ctx
    bf16*  glufb = (bf16*)(W + (80ull<<20));
    bf16*  hb    = (bf16*)(W + (80ull<<20));      // h / x1b
    bf16*  dec_out_b = (bf16*)(W + (88ull<<20));
    bf16*  img_b     = (bf16*)(W + (96ull<<20));
    bf16*  wsW   = (bf16*)(W + (104ull<<20));
    bf16* ea_wqb = wsW;                           // ea_wq|aa_wq adjacent
    bf16* aa_wqb = ea_wqb + 262144;
    bf16* ea_wob = aa_wqb + 262144;
    bf16* aa_wob = ea_wob + 262144;
    bf16* sa_wob = aa_wob + 262144;
    bf16* foldb  = sa_wob + 262144;
    bf16* ffn_w1b = foldb + 262144;
    bf16* ffn_w2b = ffn_w1b + 1048576;
    float* b_qkv    = (float*)(W + (112ull<<20)); // [1536] sa_bq|sa_bk|sa_bv
    float* bq_eaaa  = b_qkv + 1536;               // [1024] ea_bq|aa_bq
    float* b_attrkv = bq_eaaa + 1024;             // [1024] aa_bk|aa_bv
    float* b_enckv  = b_attrkv + 1024;            // [1024] ea_bk|ea_bv
    bf16* midb = (bf16*)S1;                       // [8192,2048] phase E
    // aliases inside dead x1 region (valid after phase B):
    bf16* kenc   = (bf16*)S0;                     // [3136,512]   phase C
    bf16* vt_enc = (bf16*)(W + (4ull<<20));       // [8192,256]   phase C (V^T, zero-padded)
    bf16* kvattr = (bf16*)(W + (8ull<<20));       // [320,1024] = K|V attr, phase D
    bf16* attrp  = (bf16*)(W + (10ull<<20));      // [320,320]  padded attr_out
    bf16* kvwp   = (bf16*)(W + (11ull<<20));      // [1024,320] padded aa_wk|aa_wv

    // ---- Phase 0 ----
    {
        CvtArgs ca;
        const float* srcs[16] = {conv_w, w_ih, w_hh, sa_wq, sa_wk, sa_wv, sa_wo, ea_wq,
                                 aa_wq, ea_wo, aa_wo, ffn_w1, ffn_w2, ea_wk, ea_wv, enc_outputs};
        bf16* dsts[16] = {conv_wb, w_ihb, w_hhb, sa_wqb, sa_wkb, sa_wvb, sa_wob, ea_wqb,
                          aa_wqb, ea_wob, aa_wob, ffn_w1b, ffn_w2b, ea_wkb, ea_wvb, enc_b};
        int ns[16] = {131072, 1048576, 1048576, 262144, 262144, 262144, 262144, 262144,
                      262144, 262144, 262144, 1048576, 1048576, 2097152, 2097152, 12845056};
        int cum = 0;
        for (int i = 0; i < 16; ++i) { ca.seg[i] = {srcs[i], dsts[i]}; ca.cum[i] = cum; cum += ns[i]/8; }
        ca.cum[16] = cum; ca.nseg = 16;
        k_cvt<<<(cum + 255)/256, 256, 0, stream>>>(ca);
    }
    k_fold<<<1024,256,0,stream>>>(fc_w, foldb);
    k_cat3<<<6,256,0,stream>>>(sa_bq, sa_bk, sa_bv, b_qkv);
    k_cat2<<<4,256,0,stream>>>(ea_bq, aa_bq, bq_eaaa);
    k_cat2<<<4,256,0,stream>>>(aa_bk, aa_bv, b_attrkv);
    k_cat2<<<4,256,0,stream>>>(ea_bk, ea_bv, b_enckv);

    dim3 gP(4,128), gP64(8,128), gPQ(8,128), gQKV(12,128), gX(16,64), gEKV(8,49), gA(16,128);

    // ---- Phase A: LocalRNN ----
    k_lnglu<<<8192,256,0,stream>>>(dec_inputs, rnn_a, rnn_b, glufb);
    k_gemm_fast<64,64,bf16,false><<<gP64,256,0,stream>>>(glufb,256, conv_wb,256, T0,512, nullptr, conv_b, 256);
    k_gemm_fast<128,128,bf16,false><<<gX,256,0,stream>>>(T0,512, w_ihb,512, xwb,2048, nullptr, b_ih, 512);
    k_lstm_step<<<16384,256,0,stream>>>(xwb, nullptr, b_ih, b_hh, hb, S2, 0, 1);
    k_gemm_fast<128,128,bf16,false><<<gX,256,0,stream>>>(hb,512, w_hhb,512, gb,2048, nullptr, b_hh, 512);
    k_lstm_step<<<16384,256,0,stream>>>(xwb, gb, b_ih, b_hh, hb, S2, 1, 0);
    k_gemm_fast<128,128,bf16,false><<<gX,256,0,stream>>>(hb,512, w_hhb,512, gb,2048, nullptr, b_hh, 512);
    k_lstm_last<<<16384,256,0,stream>>>(xwb, gb, dec_inputs, S2, S0, hb);      // x1 f32->S0, bf16->hb

    // ---- Phase B: causal self-attention ----
    k_gemm_fast<64,128,bf16,false,512,512,1024><<<gQKV,256,0,stream>>>(
        hb,512, sa_wqb,512, T0,1024, T2, b_qkv, 512);                          // Q|K normal, V^T->T2
    k_attn<512,512,true,true,true><<<gA,256,0,stream>>>(T0,1024, T0+512,1024, T2,0, out_sa, T3);
    k_gemm_fast<64,64,bf16,false><<<gP64,256,0,stream>>>(T3,512, sa_wob,512, T1,512, nullptr, sa_bo, 512);
    k_ln_res<float><<<8192,256,0,stream>>>(T1, S0, S1, dec_out_b, 1e-5f);

    // ---- Phase C: enc cross-attention ----
    k_zero<<<1024,256,0,stream>>>(vt_enc, 262144);
    k_gemm_fast<64,128,bf16,false><<<gPQ,256,0,stream>>>(dec_out_b,512, ea_wqb,512, T0,1024, nullptr, bq_eaaa, 512);
    k_gemm_fast<64,128,bf16,false,196,256,512><<<gEKV,256,0,stream>>>(
        enc_b,4096, ea_wkb,4096, kenc,512, vt_enc, b_enckv, 4096);             // K normal, V^T->vt_enc
    k_attn<196,256,false,true,true><<<gA,256,0,stream>>>(T0,1024, kenc,512, vt_enc,0, out_ea, T3);
    k_gemm_fast<64,64,bf16,false><<<gP64,256,0,stream>>>(T3,512, ea_wob,512, T2,512, nullptr, ea_bo, 512);
    k_ln_res<float><<<8192,256,0,stream>>>(T2, S1, S2, img_b, 1e-5f);

    // ---- Phase D: attr cross-attention ----
    k_cvt_pad<<<1680,256,0,stream>>>(attr_out, aa_wk, aa_wv, attrp, kvwp);
    { dim3 ga(8,5,1);
      k_gemm_fast<64,128,bf16,false><<<ga,256,0,stream>>>(attrp,320, kvwp,320, kvattr,1024, nullptr, b_attrkv, 320); }
    k_attn<20,20,false,false,false><<<gA,256,0,stream>>>(T0+512,1024, kvattr,1024, kvattr+512,1024, nullptr, T3);
    k_gemm_fast<64,64,bf16,false><<<gP64,256,0,stream>>>(T3,512, aa_wob,512, T2,512, nullptr, aa_bo, 512);
    k_ln_res<float><<<8192,256,0,stream>>>(T2, S1, S0, nullptr, 1e-5f);

    // ---- Phase E: gated fusion + FFN ----
    k_gemm_fast<64,64,bf16,false><<<gP64,256,0,stream>>>(img_b,512, foldb,512, T0,512, nullptr, fc_b, 512);
    k_gate_ln<<<8192,256,0,stream>>>(T0, S2, S0, norm_a, norm_b, T2);
    k_gemm_fast<128,128,bf16,true><<<gX,256,0,stream>>>(T2,512, ffn_w1b,512, midb,2048, nullptr, ffn_b1, 512);
    k_gemm_fast<64,128,bf16,false><<<gP,256,0,stream>>>(midb,2048, ffn_w2b,2048, T1,512, nullptr, ffn_b2, 2048);
    k_ln_res<bf16><<<8192,256,0,stream>>>(T1, T2, out_y, nullptr, 1e-5f);
}

// Round 15
// 692.337 us; speedup vs baseline: 1.2488x; 1.2488x over previous
//
#include <hip/hip_runtime.h>
#include <hip/hip_bf16.h>
#include <math.h>

typedef __hip_bfloat16 bf16;
typedef __attribute__((ext_vector_type(8))) short short8;
typedef __attribute__((ext_vector_type(4))) short short4v;
typedef __attribute__((ext_vector_type(4))) float f32x4;

__device__ __forceinline__ void storef(float* p, float v){ *p = v; }
__device__ __forceinline__ void storef(bf16* p, float v){ *p = __float2bfloat16(v); }
__device__ __forceinline__ float sigm(float x){ return 1.0f/(1.0f+expf(-x)); }
__device__ __forceinline__ float tof(float x){ return x; }
__device__ __forceinline__ float tof(bf16 x){ return __bfloat162float(x); }

__device__ __forceinline__ short f2bs(float f){ bf16 h=__float2bfloat16(f); short s; __builtin_memcpy(&s,&h,2); return s; }
__device__ __forceinline__ void load8(const float* __restrict__ p, short8* dst){
    const f32x4* pp = (const f32x4*)p;
    f32x4 lo = pp[0], hi = pp[1];
    short8 v;
    v[0]=f2bs(lo[0]); v[1]=f2bs(lo[1]); v[2]=f2bs(lo[2]); v[3]=f2bs(lo[3]);
    v[4]=f2bs(hi[0]); v[5]=f2bs(hi[1]); v[6]=f2bs(hi[2]); v[7]=f2bs(hi[3]);
    *dst = v;
}
__device__ __forceinline__ void load8(const bf16* __restrict__ p, short8* dst){
    *dst = *(const short8*)p;
}

__device__ __forceinline__ void gl_lds16(const bf16* g, bf16* l){
    auto gp = (const __attribute__((address_space(1))) unsigned int*)(g);
    auto lp = (__attribute__((address_space(3))) unsigned int*)(l);
    __builtin_amdgcn_global_load_lds(gp, lp, 16, 0, 0);
}

// ============ fast bf16 GEMM: C[M,N] = A[M,K] @ B[N,K]^T + bias ============
// WSEQ>0: cols >= WCUT get the transposed write to C2:
//   C2[((row/WSEQ)*8 + colv/64)*64 + colv%64][row%WSEQ], colv = col-WCUT, ld = WLDT.
template<int TM, int TN, typename OT, bool RELU, int WSEQ = 0, int WLDT = 0, int WCUT = 0>
__global__ __launch_bounds__(256) void k_gemm_fast(
    const bf16* __restrict__ A, int lda,
    const bf16* __restrict__ B, int ldb,
    OT* __restrict__ C, int ldc, bf16* __restrict__ C2,
    const float* __restrict__ bias, int K)
{
    constexpr int FM = TM/32, FN = TN/32;
    __shared__ bf16 As[TM*32];
    __shared__ bf16 Bs[TN*32];
    const int tid = threadIdx.x;
    const int wave = tid >> 6, lane = tid & 63;
    const int m0 = blockIdx.y * TM, n0 = blockIdx.x * TN;
    const int wm = (wave >> 1) * (TM/2), wn = (wave & 1) * (TN/2);
    const int lr = lane & 15, g = lane >> 4;
    const int srow = lane >> 2, sslot = (lane & 3) * 8;
    f32x4 acc[FM][FN] = {};

    for (int k0 = 0; k0 < K; k0 += 32) {
        #pragma unroll
        for (int rd = 0; rd < TM/64; ++rd) {
            int cb = rd*4 + wave;
            gl_lds16(A + (size_t)(m0 + cb*16 + srow)*lda + k0 + sslot, As + cb*512);
        }
        #pragma unroll
        for (int rd = 0; rd < TN/64; ++rd) {
            int cb = rd*4 + wave;
            gl_lds16(B + (size_t)(n0 + cb*16 + srow)*ldb + k0 + sslot, Bs + cb*512);
        }
        __syncthreads();
        short8 af[FM], bf_[FN];
        #pragma unroll
        for (int i = 0; i < FM; ++i) af[i]  = *(const short8*)&As[(wm + i*16 + lr)*32 + g*8];
        #pragma unroll
        for (int j = 0; j < FN; ++j) bf_[j] = *(const short8*)&Bs[(wn + j*16 + lr)*32 + g*8];
        #pragma unroll
        for (int i = 0; i < FM; ++i)
            #pragma unroll
            for (int j = 0; j < FN; ++j)
                acc[i][j] = __builtin_amdgcn_mfma_f32_16x16x32_bf16(af[i], bf_[j], acc[i][j], 0, 0, 0);
        __syncthreads();
    }
    const int cr4 = (lane >> 4) * 4;
    #pragma unroll
    for (int j = 0; j < FN; ++j) {
        int col = n0 + wn + j*16 + lr;
        float bv = bias[col];
        if (WSEQ > 0 && col >= WCUT) {
            int colv = col - WCUT;
            int hh = colv >> 6, dd = colv & 63;
            #pragma unroll
            for (int i = 0; i < FM; ++i) {
                int r0 = m0 + wm + i*16 + cr4;
                int bb = r0 / WSEQ, ll = r0 % WSEQ;
                short4v pk;
                #pragma unroll
                for (int q = 0; q < 4; ++q) pk[q] = f2bs(acc[i][j][q] + bv);
                *(short4v*)&C2[((size_t)(bb*8 + hh)*64 + dd)*WLDT + ll] = pk;
            }
        } else {
            #pragma unroll
            for (int i = 0; i < FM; ++i) {
                #pragma unroll
                for (int q = 0; q < 4; ++q) {
                    int row = m0 + wm + i*16 + cr4 + q;
                    float v = acc[i][j][q] + bv;
                    if (RELU) v = fmaxf(v, 0.0f);
                    storef(&C[(size_t)row*ldc + col], v);
                }
            }
        }
    }
}

// ============ fused attention ============
// VT=true: V is V^T [(b*8+h)*64+d][LKT] (padded cols >= LK are zero); PV reads global.
// CAUSAL: skip fully-masked chunks via UNROLLED loops + uniform break (acc stays in regs —
// rule #20: runtime-indexed ext_vector arrays spill to scratch).
template<int LK, int LKT, bool CAUSAL, bool WPROB, bool VT>
__global__ __launch_bounds__(256) void k_attn(
    const bf16* __restrict__ Q, int ldq, const bf16* __restrict__ K, int ldk,
    const bf16* __restrict__ V, int ldv,
    float* __restrict__ Pout, bf16* __restrict__ ctx)
{
    constexpr int LQ = 512;
    constexpr int NCH = (LK + 63) / 64;
    constexpr int LKP = NCH*64 + 8;
    __shared__ bf16 Qs[32*72];
    __shared__ bf16 Ks[64*72];
    __shared__ bf16 Ps[32*LKP];
    __shared__ float red[4][32];
    const int tid = threadIdx.x, wave = tid >> 6, lane = tid & 63;
    const int lr = lane & 15, g = lane >> 4;
    const int qt = blockIdx.x, bh = blockIdx.y;
    const int b = bh >> 3, h = bh & 7;
    const size_t qbase = (size_t)b*LQ + qt*32;
    const size_t kvbase = (size_t)b*LK;
    const int nch = CAUSAL ? ((qt >> 1) + 1) : NCH;          // active 64-col chunks (uniform)
    {
        int r = tid >> 3, c = (tid & 7) << 3;
        *(short8*)&Qs[r*72 + c] = *(const short8*)&Q[(qbase + r)*ldq + h*64 + c];
    }
    f32x4 acc[2][NCH];
    #pragma unroll
    for (int i = 0; i < 2; ++i)
        #pragma unroll
        for (int j = 0; j < NCH; ++j) acc[i][j] = (f32x4){0,0,0,0};

    #pragma unroll
    for (int ch = 0; ch < NCH; ++ch) {
        if (CAUSAL && ch >= nch) break;                      // uniform scalar branch
        __syncthreads();
        #pragma unroll
        for (int i = 0; i < 2; ++i) {
            int idx = tid + i*256;
            int r = idx >> 3, c = (idx & 7) << 3;
            int kr = ch*64 + r;
            short8 v = {};
            if (kr < LK) v = *(const short8*)&K[(kvbase + kr)*ldk + h*64 + c];
            *(short8*)&Ks[r*72 + c] = v;
        }
        __syncthreads();
        #pragma unroll
        for (int kk = 0; kk < 2; ++kk) {
            short8 bf_ = *(const short8*)&Ks[(wave*16 + lr)*72 + kk*32 + g*8];
            #pragma unroll
            for (int mi = 0; mi < 2; ++mi) {
                short8 af = *(const short8*)&Qs[(mi*16 + lr)*72 + kk*32 + g*8];
                acc[mi][ch] = __builtin_amdgcn_mfma_f32_16x16x32_bf16(af, bf_, acc[mi][ch], 0, 0, 0);
            }
        }
    }
    __syncthreads();
    // ---- softmax ----
    float rmax[2][4];
    #pragma unroll
    for (int mi = 0; mi < 2; ++mi)
        #pragma unroll
        for (int q = 0; q < 4; ++q) {
            int rowg = qt*32 + mi*16 + g*4 + q;
            float m = -INFINITY;
            #pragma unroll
            for (int ch = 0; ch < NCH; ++ch) {
                int col = ch*64 + wave*16 + lr;
                float s = acc[mi][ch][q] * 0.125f;
                if (col >= LK || (CAUSAL && col > rowg)) s = -INFINITY;
                acc[mi][ch][q] = s;
                m = fmaxf(m, s);
            }
            rmax[mi][q] = m;
        }
    #pragma unroll
    for (int off = 1; off < 16; off <<= 1)
        #pragma unroll
        for (int mi = 0; mi < 2; ++mi)
            #pragma unroll
            for (int q = 0; q < 4; ++q)
                rmax[mi][q] = fmaxf(rmax[mi][q], __shfl_xor(rmax[mi][q], off));
    if (lr == 0)
        #pragma unroll
        for (int mi = 0; mi < 2; ++mi)
            #pragma unroll
            for (int q = 0; q < 4; ++q)
                red[wave][mi*16 + g*4 + q] = rmax[mi][q];
    __syncthreads();
    float rsum[2][4];
    #pragma unroll
    for (int mi = 0; mi < 2; ++mi)
        #pragma unroll
        for (int q = 0; q < 4; ++q) {
            int rl = mi*16 + g*4 + q;
            float m = fmaxf(fmaxf(red[0][rl], red[1][rl]), fmaxf(red[2][rl], red[3][rl]));
            float s = 0.0f;
            #pragma unroll
            for (int ch = 0; ch < NCH; ++ch) {
                float e = expf(acc[mi][ch][q] - m);
                acc[mi][ch][q] = e;
                s += e;
            }
            rsum[mi][q] = s;
        }
    #pragma unroll
    for (int off = 1; off < 16; off <<= 1)
        #pragma unroll
        for (int mi = 0; mi < 2; ++mi)
            #pragma unroll
            for (int q = 0; q < 4; ++q)
                rsum[mi][q] += __shfl_xor(rsum[mi][q], off);
    __syncthreads();
    if (lr == 0)
        #pragma unroll
        for (int mi = 0; mi < 2; ++mi)
            #pragma unroll
            for (int q = 0; q < 4; ++q)
                red[wave][mi*16 + g*4 + q] = rsum[mi][q];
    __syncthreads();
    #pragma unroll
    for (int mi = 0; mi < 2; ++mi)
        #pragma unroll
        for (int q = 0; q < 4; ++q) {
            int rl = mi*16 + g*4 + q;
            float inv = 1.0f / (red[0][rl] + red[1][rl] + red[2][rl] + red[3][rl]);
            #pragma unroll
            for (int ch = 0; ch < NCH; ++ch) {
                int col = ch*64 + wave*16 + lr;
                Ps[rl*LKP + col] = __float2bfloat16(acc[mi][ch][q] * inv);
            }
        }
    __syncthreads();
    // ---- coalesced prob dump (full range; masked cols are exact 0) ----
    if (WPROB) {
        const size_t pbase = ((size_t)bh*LQ + qt*32)*LK;
        constexpr int NV = 32*LK/4;
        for (int p = tid; p < NV; p += 256) {
            int e = p*4;
            int row = e / LK, col = e % LK;
            f32x4 v;
            #pragma unroll
            for (int u = 0; u < 4; ++u) v[u] = tof(Ps[row*LKP + col + u]);
            *(f32x4*)&Pout[pbase + (size_t)row*LK + col] = v;
        }
    }
    // ---- PV ----
    const int pcmax = CAUSAL ? (qt + 1) : 2*NCH;             // active 32-col chunks (uniform)
    f32x4 o[2] = {(f32x4){0,0,0,0},(f32x4){0,0,0,0}};
    if constexpr (VT) {
        const bf16* vrow = V + ((size_t)(b*8 + h)*64 + wave*16 + lr)*LKT;
        #pragma unroll
        for (int pc = 0; pc < 2*NCH; ++pc) {
            if (CAUSAL && pc >= pcmax) break;
            short8 bf_ = *(const short8*)&vrow[pc*32 + g*8];
            #pragma unroll
            for (int mi = 0; mi < 2; ++mi) {
                short8 af = *(const short8*)&Ps[(mi*16 + lr)*LKP + pc*32 + g*8];
                o[mi] = __builtin_amdgcn_mfma_f32_16x16x32_bf16(af, bf_, o[mi], 0, 0, 0);
            }
        }
    } else {
        short* Vs = (short*)Ks;
        #pragma unroll
        for (int pc = 0; pc < 2*NCH; ++pc) {
            if (CAUSAL && pc >= pcmax) break;
            __syncthreads();
            {
                int r = tid >> 3, c = (tid & 7) << 3;
                int kr = pc*32 + r;
                short8 v = {};
                if (kr < LK) v = *(const short8*)&V[(kvbase + kr)*ldv + h*64 + c];
                #pragma unroll
                for (int j = 0; j < 8; ++j) Vs[(c + j)*40 + r] = v[j];
            }
            __syncthreads();
            short8 bf_ = *(const short8*)&Vs[(wave*16 + lr)*40 + g*8];
            #pragma unroll
            for (int mi = 0; mi < 2; ++mi) {
                short8 af = *(const short8*)&Ps[(mi*16 + lr)*LKP + pc*32 + g*8];
                o[mi] = __builtin_amdgcn_mfma_f32_16x16x32_bf16(af, bf_, o[mi], 0, 0, 0);
            }
        }
    }
    const int cr4g = g * 4;
    #pragma unroll
    for (int mi = 0; mi < 2; ++mi)
        #pragma unroll
        for (int q = 0; q < 4; ++q) {
            int rl = mi*16 + cr4g + q;
            storef(&ctx[(qbase + rl)*512 + h*64 + wave*16 + lr], o[mi][q]);
        }
}

// ---------------- bulk f32 -> bf16 converter
struct CvtSeg { const float* src; bf16* dst; };
struct CvtArgs { CvtSeg seg[16]; int cum[17]; int nseg; };
__global__ void k_cvt(CvtArgs a)
{
    int gid = blockIdx.x*256 + threadIdx.x;
    if (gid >= a.cum[a.nseg]) return;
    int s = 0;
    while (s < a.nseg-1 && gid >= a.cum[s+1]) ++s;
    int off = (gid - a.cum[s]) * 8;
    short8 v; load8(a.seg[s].src + off, &v);
    *(short8*)(a.seg[s].dst + off) = v;
}

// ---------------- attr pad-convert
__global__ void k_cvt_pad(const float* __restrict__ a, const float* __restrict__ wk,
                          const float* __restrict__ wv, bf16* __restrict__ attrp,
                          bf16* __restrict__ kvwp)
{
    int t = blockIdx.x*256 + threadIdx.x;     // 1344*320
    if (t >= 1344*320) return;
    int r = t / 320, c = t % 320;
    float v = 0.0f;
    if (c < 300) {
        if (r < 320) v = a[(size_t)r*300 + c];
        else if (r < 832) v = wk[(size_t)(r-320)*300 + c];
        else v = wv[(size_t)(r-832)*300 + c];
    }
    if (r < 320) storef(&attrp[(size_t)r*320 + c], v);
    else storef(&kvwp[(size_t)(r-320)*320 + c], v);
}

__global__ void k_cat2(const float* __restrict__ a, const float* __restrict__ b,
                       float* __restrict__ dst)
{
    int t = blockIdx.x*256 + threadIdx.x;
    if (t < 512) dst[t] = a[t];
    else if (t < 1024) dst[t] = b[t-512];
}

__global__ void k_cat3(const float* __restrict__ a, const float* __restrict__ b,
                       const float* __restrict__ c, float* __restrict__ dst)
{
    int t = blockIdx.x*256 + threadIdx.x;
    if (t < 512) dst[t] = a[t];
    else if (t < 1024) dst[t] = b[t-512];
    else if (t < 1536) dst[t] = c[t-1024];
}

__global__ void k_zero(bf16* __restrict__ p, int n8)
{
    int t = blockIdx.x*256 + threadIdx.x;
    if (t < n8) { short8 z = {}; *(short8*)&p[t*8] = z; }
}

// ---------------- fused custom-LN + GLU -> bf16 [8192,256]
__global__ void k_lnglu(const float* __restrict__ x, const float* __restrict__ a,
                        const float* __restrict__ bpar, bf16* __restrict__ out)
{
    int r = blockIdx.x, tid = threadIdx.x;
    const float* xr = x + (size_t)r*512;
    float v0 = xr[tid], v1 = xr[tid+256];
    __shared__ float red[256];
    red[tid] = v0+v1; __syncthreads();
    for (int s=128;s>0;s>>=1){ if(tid<s) red[tid]+=red[tid+s]; __syncthreads(); }
    float mean = red[0]*(1.0f/512.0f); __syncthreads();
    float d0 = v0-mean, d1 = v1-mean;
    red[tid] = d0*d0+d1*d1; __syncthreads();
    for (int s=128;s>0;s>>=1){ if(tid<s) red[tid]+=red[tid+s]; __syncthreads(); }
    float stdv = sqrtf(red[0]*(1.0f/511.0f));
    float inv = 1.0f/(stdv + 1e-6f);
    float o0 = a[tid]    *d0*inv + bpar[tid];
    float o1 = a[tid+256]*d1*inv + bpar[tid+256];
    storef(&out[(size_t)r*256 + tid], o0 * sigm(o1));
}

// ---------------- LSTM steps t=0,1
__global__ void k_lstm_step(const bf16* __restrict__ XW, const bf16* __restrict__ G,
                            const float* __restrict__ bih, const float* __restrict__ bhh,
                            bf16* __restrict__ h, float* __restrict__ c, int t, int first)
{
    int idx = blockIdx.x*256 + threadIdx.x;
    int n = idx >> 9, j = idx & 511;
    int b = n >> 9, l = n & 511;
    int lp = l - 2 + t;
    float gi, gf, gg, go;
    if (lp >= 0) {
        const bf16* xr = XW + ((size_t)(b*512 + lp))*2048;
        gi = tof(xr[j]); gf = tof(xr[512+j]); gg = tof(xr[1024+j]); go = tof(xr[1536+j]);
    } else {
        gi = bih[j]; gf = bih[512+j]; gg = bih[1024+j]; go = bih[1536+j];
    }
    if (first) {
        gi += bhh[j]; gf += bhh[512+j]; gg += bhh[1024+j]; go += bhh[1536+j];
        float cn = sigm(gi)*tanhf(gg);
        c[idx] = cn;
        storef(&h[idx], sigm(go)*tanhf(cn));
    } else {
        const bf16* gr = G + (size_t)n*2048;
        gi += tof(gr[j]); gf += tof(gr[512+j]); gg += tof(gr[1024+j]); go += tof(gr[1536+j]);
        float cn = sigm(gf)*c[idx] + sigm(gi)*tanhf(gg);
        c[idx] = cn;
        storef(&h[idx], sigm(go)*tanhf(cn));
    }
}

// ---------------- LSTM final step t=2 fused with residual add: x1 = dec + h
__global__ void k_lstm_last(const bf16* __restrict__ XW, const bf16* __restrict__ G,
                            const float* __restrict__ dec, const float* __restrict__ c,
                            float* __restrict__ x1f, bf16* __restrict__ x1b)
{
    int idx = blockIdx.x*256 + threadIdx.x;
    int n = idx >> 9, j = idx & 511;
    int b = n >> 9, l = n & 511;
    const bf16* xr = XW + ((size_t)(b*512 + l))*2048;
    float gi = tof(xr[j]), gf = tof(xr[512+j]), gg = tof(xr[1024+j]), go = tof(xr[1536+j]);
    const bf16* gr = G + (size_t)n*2048;
    gi += tof(gr[j]); gf += tof(gr[512+j]); gg += tof(gr[1024+j]); go += tof(gr[1536+j]);
    float cn = sigm(gf)*c[idx] + sigm(gi)*tanhf(gg);
    float h = sigm(go)*tanhf(cn);
    float v = dec[idx] + h;
    x1f[idx] = v;
    storef(&x1b[idx], v);
}

template<typename RT>
__global__ void k_ln_res(const bf16* __restrict__ x, const RT* __restrict__ res,
                         float* __restrict__ out, bf16* __restrict__ outb, float eps)
{
    int r = blockIdx.x, tid = threadIdx.x;
    const bf16* xr = x + (size_t)r*512;
    const RT* rr = res + (size_t)r*512;
    float v0 = tof(xr[tid]) + tof(rr[tid]), v1 = tof(xr[tid+256]) + tof(rr[tid+256]);
    __shared__ float red[256];
    red[tid] = v0+v1; __syncthreads();
    for (int s=128;s>0;s>>=1){ if(tid<s) red[tid]+=red[tid+s]; __syncthreads(); }
    float mean = red[0]*(1.0f/512.0f); __syncthreads();
    float d0 = v0-mean, d1 = v1-mean;
    red[tid] = d0*d0+d1*d1; __syncthreads();
    for (int s=128;s>0;s>>=1){ if(tid<s) red[tid]+=red[tid+s]; __syncthreads(); }
    float inv = rsqrtf(red[0]*(1.0f/512.0f) + eps);
    float o0 = d0*inv, o1 = d1*inv;
    out[(size_t)r*512 + tid]     = o0;
    out[(size_t)r*512 + tid+256] = o1;
    if (outb) {
        storef(&outb[(size_t)r*512 + tid],     o0);
        storef(&outb[(size_t)r*512 + tid+256], o1);
    }
}

__global__ void k_gate_ln(const bf16* __restrict__ ctpre, const float* __restrict__ img,
                          const float* __restrict__ attr, const float* __restrict__ na,
                          const float* __restrict__ nb, bf16* __restrict__ out)
{
    int r = blockIdx.x, tid = threadIdx.x;
    size_t base = (size_t)r*512;
    float ct0 = sigm(tof(ctpre[base+tid]));
    float v0 = ct0*fmaxf(img[base+tid],0.f) + (1.f-ct0)*fmaxf(attr[base+tid],0.f);
    float ct1 = sigm(tof(ctpre[base+tid+256]));
    float v1 = ct1*fmaxf(img[base+tid+256],0.f) + (1.f-ct1)*fmaxf(attr[base+tid+256],0.f);
    __shared__ float red[256];
    red[tid] = v0+v1; __syncthreads();
    for (int s=128;s>0;s>>=1){ if(tid<s) red[tid]+=red[tid+s]; __syncthreads(); }
    float mean = red[0]*(1.0f/512.0f); __syncthreads();
    float d0 = v0-mean, d1 = v1-mean;
    red[tid] = d0*d0+d1*d1; __syncthreads();
    for (int s=128;s>0;s>>=1){ if(tid<s) red[tid]+=red[tid+s]; __syncthreads(); }
    float stdv = sqrtf(red[0]*(1.0f/511.0f));
    float inv = 1.0f/(stdv + 1e-6f);
    storef(&out[base+tid],     na[tid]    *d0*inv + nb[tid]);
    storef(&out[base+tid+256], na[tid+256]*d1*inv + nb[tid+256]);
}

__global__ void k_fold(const float* __restrict__ fcw, bf16* __restrict__ fold)
{
    int idx = blockIdx.x*256 + threadIdx.x;
    int d = idx >> 9, j = idx & 511;
    storef(&fold[idx], fcw[(size_t)d*1024 + j] + fcw[(size_t)d*1024 + 512 + j]);
}

extern "C" void kernel_launch(void* const* d_in, const int* in_sizes, int n_in,
                              void* d_out, int out_size, void* d_ws, size_t ws_size,
                              hipStream_t stream)
{
    const float* dec_inputs  = (const float*)d_in[0];
    const float* enc_outputs = (const float*)d_in[1];
    const float* attr_out    = (const float*)d_in[2];
    const float* rnn_a  = (const float*)d_in[6];
    const float* rnn_b  = (const float*)d_in[7];
    const float* conv_w = (const float*)d_in[8];
    const float* conv_b = (const float*)d_in[9];
    const float* w_ih   = (const float*)d_in[10];
    const float* w_hh   = (const float*)d_in[11];
    const float* b_ih   = (const float*)d_in[12];
    const float* b_hh   = (const float*)d_in[13];
    const float* sa_wq  = (const float*)d_in[14]; const float* sa_bq = (const float*)d_in[15];
    const float* sa_wk  = (const float*)d_in[16]; const float* sa_bk = (const float*)d_in[17];
    const float* sa_wv  = (const float*)d_in[18]; const float* sa_bv = (const float*)d_in[19];
    const float* sa_wo  = (const float*)d_in[20]; const float* sa_bo = (const float*)d_in[21];
    const float* ea_wq  = (const float*)d_in[22]; const float* ea_bq = (const float*)d_in[23];
    const float* ea_wk  = (const float*)d_in[24]; const float* ea_bk = (const float*)d_in[25];
    const float* ea_wv  = (const float*)d_in[26]; const float* ea_bv = (const float*)d_in[27];
    const float* ea_wo  = (const float*)d_in[28]; const float* ea_bo = (const float*)d_in[29];
    const float* aa_wq  = (const float*)d_in[30]; const float* aa_bq = (const float*)d_in[31];
    const float* aa_wk  = (const float*)d_in[32]; const float* aa_bk = (const float*)d_in[33];
    const float* aa_wv  = (const float*)d_in[34]; const float* aa_bv = (const float*)d_in[35];
    const float* aa_wo  = (const float*)d_in[36]; const float* aa_bo = (const float*)d_in[37];
    const float* fc_w   = (const float*)d_in[38]; const float* fc_b  = (const float*)d_in[39];
    const float* norm_a = (const float*)d_in[40]; const float* norm_b= (const float*)d_in[41];
    const float* ffn_w1 = (const float*)d_in[42]; const float* ffn_b1= (const float*)d_in[43];
    const float* ffn_w2 = (const float*)d_in[44]; const float* ffn_b2= (const float*)d_in[45];

    float* out_y  = (float*)d_out;
    float* out_sa = out_y + 4194304ull;      // [16,8,512,512] f32
    float* out_ea = out_sa + 33554432ull;    // [16,8,512,196] f32

    // scratch inside out_sa (dead until k_attn<self> writes it)
    bf16* xwb = (bf16*)out_sa;                    // [8192,2048]
    bf16* gb  = xwb + 16777216ull;
    bf16* wA  = (bf16*)(out_sa + 16777216ull);
    bf16* conv_wb = wA;
    bf16* w_ihb   = conv_wb + 131072;
    bf16* w_hhb   = w_ihb + 1048576;
    bf16* sa_wqb  = w_hhb + 1048576;              // wq|wk|wv adjacent (fused QKV)
    bf16* sa_wkb  = sa_wqb + 262144;
    bf16* sa_wvb  = sa_wkb + 262144;
    // scratch inside out_ea (dead until k_attn<enc> writes it)
    bf16* enc_b   = (bf16*)out_ea;                // [3136,4096]
    bf16* ea_wkb  = (bf16*)(out_ea + 6422528ull); // wk|wv adjacent (fused KV)
    bf16* ea_wvb  = ea_wkb + 2097152;

    char* W = (char*)d_ws;
    float* S0 = (float*)(W);                      // x1 / attr ; aliases (dead phases)
    float* S1 = (float*)(W + (16ull<<20));        // dec_out ; midb in E
    float* S2 = (float*)(W + (32ull<<20));        // c / img
    bf16*  T0 = (bf16*) (W + (48ull<<20));        // fat q|k [8192,1024] spans T0..T1 / ctpre
    bf16*  T1 = (bf16*) (W + (56ull<<20));        // proj out / ffn2out
    bf16*  T2 = (bf16*) (W + (64ull<<20));        // vt_self / proj out / y1
    bf16*  T3 = (bf16*) (W + (72ull<<20));        // ctx
    bf16*  glufb = (bf16*)(W + (80ull<<20));
    bf16*  hb    = (bf16*)(W + (80ull<<20));      // h / x1b
    bf16*  dec_out_b = (bf16*)(W + (88ull<<20));
    bf16*  img_b     = (bf16*)(W + (96ull<<20));
    bf16*  wsW   = (bf16*)(W + (104ull<<20));
    bf16* ea_wqb = wsW;                           // ea_wq|aa_wq adjacent
    bf16* aa_wqb = ea_wqb + 262144;
    bf16* ea_wob = aa_wqb + 262144;
    bf16* aa_wob = ea_wob + 262144;
    bf16* sa_wob = aa_wob + 262144;
    bf16* foldb  = sa_wob + 262144;
    bf16* ffn_w1b = foldb + 262144;
    bf16* ffn_w2b = ffn_w1b + 1048576;
    float* b_qkv    = (float*)(W + (112ull<<20)); // [1536] sa_bq|sa_bk|sa_bv
    float* bq_eaaa  = b_qkv + 1536;               // [1024] ea_bq|aa_bq
    float* b_attrkv = bq_eaaa + 1024;             // [1024] aa_bk|aa_bv
    float* b_enckv  = b_attrkv + 1024;            // [1024] ea_bk|ea_bv
    bf16* midb = (bf16*)S1;                       // [8192,2048] phase E
    // aliases inside dead x1 region (valid after phase B):
    bf16* kenc   = (bf16*)S0;                     // [3136,512]   phase C
    bf16* vt_enc = (bf16*)(W + (4ull<<20));       // [8192,256]   phase C (V^T, zero-padded)
    bf16* kvattr = (bf16*)(W + (8ull<<20));       // [320,1024] = K|V attr, phase D
    bf16* attrp  = (bf16*)(W + (10ull<<20));      // [320,320]  padded attr_out
    bf16* kvwp   = (bf16*)(W + (11ull<<20));      // [1024,320] padded aa_wk|aa_wv

    // ---- Phase 0 ----
    {
        CvtArgs ca;
        const float* srcs[16] = {conv_w, w_ih, w_hh, sa_wq, sa_wk, sa_wv, sa_wo, ea_wq,
                                 aa_wq, ea_wo, aa_wo, ffn_w1, ffn_w2, ea_wk, ea_wv, enc_outputs};
        bf16* dsts[16] = {conv_wb, w_ihb, w_hhb, sa_wqb, sa_wkb, sa_wvb, sa_wob, ea_wqb,
                          aa_wqb, ea_wob, aa_wob, ffn_w1b, ffn_w2b, ea_wkb, ea_wvb, enc_b};
        int ns[16] = {131072, 1048576, 1048576, 262144, 262144, 262144, 262144, 262144,
                      262144, 262144, 262144, 1048576, 1048576, 2097152, 2097152, 12845056};
        int cum = 0;
        for (int i = 0; i < 16; ++i) { ca.seg[i] = {srcs[i], dsts[i]}; ca.cum[i] = cum; cum += ns[i]/8; }
        ca.cum[16] = cum; ca.nseg = 16;
        k_cvt<<<(cum + 255)/256, 256, 0, stream>>>(ca);
    }
    k_fold<<<1024,256,0,stream>>>(fc_w, foldb);
    k_cat3<<<6,256,0,stream>>>(sa_bq, sa_bk, sa_bv, b_qkv);
    k_cat2<<<4,256,0,stream>>>(ea_bq, aa_bq, bq_eaaa);
    k_cat2<<<4,256,0,stream>>>(aa_bk, aa_bv, b_attrkv);
    k_cat2<<<4,256,0,stream>>>(ea_bk, ea_bv, b_enckv);

    dim3 gP(4,128), gP64(8,128), gPQ(8,128), gQKV(12,128), gX(16,64), gEKV(8,49), gA(16,128);

    // ---- Phase A: LocalRNN ----
    k_lnglu<<<8192,256,0,stream>>>(dec_inputs, rnn_a, rnn_b, glufb);
    k_gemm_fast<64,64,bf16,false><<<gP64,256,0,stream>>>(glufb,256, conv_wb,256, T0,512, nullptr, conv_b, 256);
    k_gemm_fast<128,128,bf16,false><<<gX,256,0,stream>>>(T0,512, w_ihb,512, xwb,2048, nullptr, b_ih, 512);
    k_lstm_step<<<16384,256,0,stream>>>(xwb, nullptr, b_ih, b_hh, hb, S2, 0, 1);
    k_gemm_fast<128,128,bf16,false><<<gX,256,0,stream>>>(hb,512, w_hhb,512, gb,2048, nullptr, b_hh, 512);
    k_lstm_step<<<16384,256,0,stream>>>(xwb, gb, b_ih, b_hh, hb, S2, 1, 0);
    k_gemm_fast<128,128,bf16,false><<<gX,256,0,stream>>>(hb,512, w_hhb,512, gb,2048, nullptr, b_hh, 512);
    k_lstm_last<<<16384,256,0,stream>>>(xwb, gb, dec_inputs, S2, S0, hb);      // x1 f32->S0, bf16->hb

    // ---- Phase B: causal self-attention ----
    k_gemm_fast<64,128,bf16,false,512,512,1024><<<gQKV,256,0,stream>>>(
        hb,512, sa_wqb,512, T0,1024, T2, b_qkv, 512);                          // Q|K normal, V^T->T2
    k_attn<512,512,true,true,true><<<gA,256,0,stream>>>(T0,1024, T0+512,1024, T2,0, out_sa, T3);
    k_gemm_fast<64,64,bf16,false><<<gP64,256,0,stream>>>(T3,512, sa_wob,512, T1,512, nullptr, sa_bo, 512);
    k_ln_res<float><<<8192,256,0,stream>>>(T1, S0, S1, dec_out_b, 1e-5f);

    // ---- Phase C: enc cross-attention ----
    k_zero<<<1024,256,0,stream>>>(vt_enc, 262144);
    k_gemm_fast<64,128,bf16,false><<<gPQ,256,0,stream>>>(dec_out_b,512, ea_wqb,512, T0,1024, nullptr, bq_eaaa, 512);
    k_gemm_fast<64,128,bf16,false,196,256,512><<<gEKV,256,0,stream>>>(
        enc_b,4096, ea_wkb,4096, kenc,512, vt_enc, b_enckv, 4096);             // K normal, V^T->vt_enc
    k_attn<196,256,false,true,true><<<gA,256,0,stream>>>(T0,1024, kenc,512, vt_enc,0, out_ea, T3);
    k_gemm_fast<64,64,bf16,false><<<gP64,256,0,stream>>>(T3,512, ea_wob,512, T2,512, nullptr, ea_bo, 512);
    k_ln_res<float><<<8192,256,0,stream>>>(T2, S1, S2, img_b, 1e-5f);

    // ---- Phase D: attr cross-attention ----
    k_cvt_pad<<<1680,256,0,stream>>>(attr_out, aa_wk, aa_wv, attrp, kvwp);
    { dim3 ga(8,5,1);
      k_gemm_fast<64,128,bf16,false><<<ga,256,0,stream>>>(attrp,320, kvwp,320, kvattr,1024, nullptr, b_attrkv, 320); }
    k_attn<20,20,false,false,false><<<gA,256,0,stream>>>(T0+512,1024, kvattr,1024, kvattr+512,1024, nullptr, T3);
    k_gemm_fast<64,64,bf16,false><<<gP64,256,0,stream>>>(T3,512, aa_wob,512, T2,512, nullptr, aa_bo, 512);
    k_ln_res<float><<<8192,256,0,stream>>>(T2, S1, S0, nullptr, 1e-5f);

    // ---- Phase E: gated fusion + FFN ----
    k_gemm_fast<64,64,bf16,false><<<gP64,256,0,stream>>>(img_b,512, foldb,512, T0,512, nullptr, fc_b, 512);
    k_gate_ln<<<8192,256,0,stream>>>(T0, S2, S0, norm_a, norm_b, T2);
    k_gemm_fast<128,128,bf16,true><<<gX,256,0,stream>>>(T2,512, ffn_w1b,512, midb,2048, nullptr, ffn_b1, 512);
    k_gemm_fast<64,128,bf16,false><<<gP,256,0,stream>>>(midb,2048, ffn_w2b,2048, T1,512, nullptr, ffn_b2, 2048);
    k_ln_res<bf16><<<8192,256,0,stream>>>(T1, T2, out_y, nullptr, 1e-5f);
}

// Round 16
// 679.672 us; speedup vs baseline: 1.2720x; 1.0186x over previous
//
#include <hip/hip_runtime.h>
#include <hip/hip_bf16.h>
#include <math.h>

typedef __hip_bfloat16 bf16;
typedef __attribute__((ext_vector_type(8))) short short8;
typedef __attribute__((ext_vector_type(4))) short short4v;
typedef __attribute__((ext_vector_type(4))) float f32x4;

__device__ __forceinline__ void storef(float* p, float v){ *p = v; }
__device__ __forceinline__ void storef(bf16* p, float v){ *p = __float2bfloat16(v); }
__device__ __forceinline__ float sigm(float x){ return 1.0f/(1.0f+expf(-x)); }
__device__ __forceinline__ float tof(float x){ return x; }
__device__ __forceinline__ float tof(bf16 x){ return __bfloat162float(x); }

__device__ __forceinline__ short f2bs(float f){ bf16 h=__float2bfloat16(f); short s; __builtin_memcpy(&s,&h,2); return s; }
__device__ __forceinline__ void load8(const float* __restrict__ p, short8* dst){
    const f32x4* pp = (const f32x4*)p;
    f32x4 lo = pp[0], hi = pp[1];
    short8 v;
    v[0]=f2bs(lo[0]); v[1]=f2bs(lo[1]); v[2]=f2bs(lo[2]); v[3]=f2bs(lo[3]);
    v[4]=f2bs(hi[0]); v[5]=f2bs(hi[1]); v[6]=f2bs(hi[2]); v[7]=f2bs(hi[3]);
    *dst = v;
}
__device__ __forceinline__ void load8(const bf16* __restrict__ p, short8* dst){
    *dst = *(const short8*)p;
}

__device__ __forceinline__ void gl_lds16(const bf16* g, bf16* l){
    auto gp = (const __attribute__((address_space(1))) unsigned int*)(g);
    auto lp = (__attribute__((address_space(3))) unsigned int*)(l);
    __builtin_amdgcn_global_load_lds(gp, lp, 16, 0, 0);
}

// ============ fast bf16 GEMM: C[M,N] = A[M,K] @ B[N,K]^T + bias ============
// WSEQ>0: cols >= WCUT get the transposed write to C2:
//   C2[((row/WSEQ)*8 + colv/64)*64 + colv%64][row%WSEQ], colv = col-WCUT, ld = WLDT.
template<int TM, int TN, typename OT, bool RELU, int WSEQ = 0, int WLDT = 0, int WCUT = 0>
__global__ __launch_bounds__(256) void k_gemm_fast(
    const bf16* __restrict__ A, int lda,
    const bf16* __restrict__ B, int ldb,
    OT* __restrict__ C, int ldc, bf16* __restrict__ C2,
    const float* __restrict__ bias, int K)
{
    constexpr int FM = TM/32, FN = TN/32;
    __shared__ bf16 As[TM*32];
    __shared__ bf16 Bs[TN*32];
    const int tid = threadIdx.x;
    const int wave = tid >> 6, lane = tid & 63;
    const int m0 = blockIdx.y * TM, n0 = blockIdx.x * TN;
    const int wm = (wave >> 1) * (TM/2), wn = (wave & 1) * (TN/2);
    const int lr = lane & 15, g = lane >> 4;
    const int srow = lane >> 2, sslot = (lane & 3) * 8;
    f32x4 acc[FM][FN] = {};

    for (int k0 = 0; k0 < K; k0 += 32) {
        #pragma unroll
        for (int rd = 0; rd < TM/64; ++rd) {
            int cb = rd*4 + wave;
            gl_lds16(A + (size_t)(m0 + cb*16 + srow)*lda + k0 + sslot, As + cb*512);
        }
        #pragma unroll
        for (int rd = 0; rd < TN/64; ++rd) {
            int cb = rd*4 + wave;
            gl_lds16(B + (size_t)(n0 + cb*16 + srow)*ldb + k0 + sslot, Bs + cb*512);
        }
        __syncthreads();
        short8 af[FM], bf_[FN];
        #pragma unroll
        for (int i = 0; i < FM; ++i) af[i]  = *(const short8*)&As[(wm + i*16 + lr)*32 + g*8];
        #pragma unroll
        for (int j = 0; j < FN; ++j) bf_[j] = *(const short8*)&Bs[(wn + j*16 + lr)*32 + g*8];
        #pragma unroll
        for (int i = 0; i < FM; ++i)
            #pragma unroll
            for (int j = 0; j < FN; ++j)
                acc[i][j] = __builtin_amdgcn_mfma_f32_16x16x32_bf16(af[i], bf_[j], acc[i][j], 0, 0, 0);
        __syncthreads();
    }
    const int cr4 = (lane >> 4) * 4;
    #pragma unroll
    for (int j = 0; j < FN; ++j) {
        int col = n0 + wn + j*16 + lr;
        float bv = bias[col];
        if (WSEQ > 0 && col >= WCUT) {
            int colv = col - WCUT;
            int hh = colv >> 6, dd = colv & 63;
            #pragma unroll
            for (int i = 0; i < FM; ++i) {
                int r0 = m0 + wm + i*16 + cr4;
                int bb = r0 / WSEQ, ll = r0 % WSEQ;
                short4v pk;
                #pragma unroll
                for (int q = 0; q < 4; ++q) pk[q] = f2bs(acc[i][j][q] + bv);
                *(short4v*)&C2[((size_t)(bb*8 + hh)*64 + dd)*WLDT + ll] = pk;
            }
        } else {
            #pragma unroll
            for (int i = 0; i < FM; ++i) {
                #pragma unroll
                for (int q = 0; q < 4; ++q) {
                    int row = m0 + wm + i*16 + cr4 + q;
                    float v = acc[i][j][q] + bv;
                    if (RELU) v = fmaxf(v, 0.0f);
                    storef(&C[(size_t)row*ldc + col], v);
                }
            }
        }
    }
}

// ============ fused attention ============
// VT=true: V is V^T [(b*8+h)*64+d][LKT] (padded cols >= LK are zero); PV reads global.
template<int LK, int LKT, bool CAUSAL, bool WPROB, bool VT>
__global__ __launch_bounds__(256) void k_attn(
    const bf16* __restrict__ Q, int ldq, const bf16* __restrict__ K, int ldk,
    const bf16* __restrict__ V, int ldv,
    float* __restrict__ Pout, bf16* __restrict__ ctx)
{
    constexpr int LQ = 512;
    constexpr int NCH = (LK + 63) / 64;
    constexpr int LKP = NCH*64 + 8;
    __shared__ bf16 Qs[32*72];
    __shared__ bf16 Ks[64*72];
    __shared__ bf16 Ps[32*LKP];
    __shared__ float red[4][32];
    const int tid = threadIdx.x, wave = tid >> 6, lane = tid & 63;
    const int lr = lane & 15, g = lane >> 4;
    const int qt = blockIdx.x, bh = blockIdx.y;
    const int b = bh >> 3, h = bh & 7;
    const size_t qbase = (size_t)b*LQ + qt*32;
    const size_t kvbase = (size_t)b*LK;
    {
        int r = tid >> 3, c = (tid & 7) << 3;
        *(short8*)&Qs[r*72 + c] = *(const short8*)&Q[(qbase + r)*ldq + h*64 + c];
    }
    f32x4 acc[2][NCH];
    #pragma unroll
    for (int i = 0; i < 2; ++i)
        #pragma unroll
        for (int j = 0; j < NCH; ++j) acc[i][j] = (f32x4){0,0,0,0};

    for (int ch = 0; ch < NCH; ++ch) {
        __syncthreads();
        #pragma unroll
        for (int i = 0; i < 2; ++i) {
            int idx = tid + i*256;
            int r = idx >> 3, c = (idx & 7) << 3;
            int kr = ch*64 + r;
            short8 v = {};
            if (kr < LK) v = *(const short8*)&K[(kvbase + kr)*ldk + h*64 + c];
            *(short8*)&Ks[r*72 + c] = v;
        }
        __syncthreads();
        #pragma unroll
        for (int kk = 0; kk < 2; ++kk) {
            short8 bf_ = *(const short8*)&Ks[(wave*16 + lr)*72 + kk*32 + g*8];
            #pragma unroll
            for (int mi = 0; mi < 2; ++mi) {
                short8 af = *(const short8*)&Qs[(mi*16 + lr)*72 + kk*32 + g*8];
                acc[mi][ch] = __builtin_amdgcn_mfma_f32_16x16x32_bf16(af, bf_, acc[mi][ch], 0, 0, 0);
            }
        }
    }
    __syncthreads();
    // ---- softmax ----
    float rmax[2][4];
    #pragma unroll
    for (int mi = 0; mi < 2; ++mi)
        #pragma unroll
        for (int q = 0; q < 4; ++q) {
            int rowg = qt*32 + mi*16 + g*4 + q;
            float m = -INFINITY;
            #pragma unroll
            for (int ch = 0; ch < NCH; ++ch) {
                int col = ch*64 + wave*16 + lr;
                float s = acc[mi][ch][q] * 0.125f;
                if (col >= LK || (CAUSAL && col > rowg)) s = -INFINITY;
                acc[mi][ch][q] = s;
                m = fmaxf(m, s);
            }
            rmax[mi][q] = m;
        }
    #pragma unroll
    for (int off = 1; off < 16; off <<= 1)
        #pragma unroll
        for (int mi = 0; mi < 2; ++mi)
            #pragma unroll
            for (int q = 0; q < 4; ++q)
                rmax[mi][q] = fmaxf(rmax[mi][q], __shfl_xor(rmax[mi][q], off));
    if (lr == 0)
        #pragma unroll
        for (int mi = 0; mi < 2; ++mi)
            #pragma unroll
            for (int q = 0; q < 4; ++q)
                red[wave][mi*16 + g*4 + q] = rmax[mi][q];
    __syncthreads();
    float rsum[2][4];
    #pragma unroll
    for (int mi = 0; mi < 2; ++mi)
        #pragma unroll
        for (int q = 0; q < 4; ++q) {
            int rl = mi*16 + g*4 + q;
            float m = fmaxf(fmaxf(red[0][rl], red[1][rl]), fmaxf(red[2][rl], red[3][rl]));
            float s = 0.0f;
            #pragma unroll
            for (int ch = 0; ch < NCH; ++ch) {
                float e = expf(acc[mi][ch][q] - m);
                acc[mi][ch][q] = e;
                s += e;
            }
            rsum[mi][q] = s;
        }
    #pragma unroll
    for (int off = 1; off < 16; off <<= 1)
        #pragma unroll
        for (int mi = 0; mi < 2; ++mi)
            #pragma unroll
            for (int q = 0; q < 4; ++q)
                rsum[mi][q] += __shfl_xor(rsum[mi][q], off);
    __syncthreads();
    if (lr == 0)
        #pragma unroll
        for (int mi = 0; mi < 2; ++mi)
            #pragma unroll
            for (int q = 0; q < 4; ++q)
                red[wave][mi*16 + g*4 + q] = rsum[mi][q];
    __syncthreads();
    #pragma unroll
    for (int mi = 0; mi < 2; ++mi)
        #pragma unroll
        for (int q = 0; q < 4; ++q) {
            int rl = mi*16 + g*4 + q;
            float inv = 1.0f / (red[0][rl] + red[1][rl] + red[2][rl] + red[3][rl]);
            #pragma unroll
            for (int ch = 0; ch < NCH; ++ch) {
                int col = ch*64 + wave*16 + lr;
                Ps[rl*LKP + col] = __float2bfloat16(acc[mi][ch][q] * inv);
            }
        }
    __syncthreads();
    // ---- coalesced prob dump (full range; masked cols are exact 0) ----
    if (WPROB) {
        const size_t pbase = ((size_t)bh*LQ + qt*32)*LK;
        constexpr int NV = 32*LK/4;
        for (int p = tid; p < NV; p += 256) {
            int e = p*4;
            int row = e / LK, col = e % LK;
            f32x4 v;
            #pragma unroll
            for (int u = 0; u < 4; ++u) v[u] = tof(Ps[row*LKP + col + u]);
            *(f32x4*)&Pout[pbase + (size_t)row*LK + col] = v;
        }
    }
    // ---- PV ----
    f32x4 o[2] = {(f32x4){0,0,0,0},(f32x4){0,0,0,0}};
    if constexpr (VT) {
        const bf16* vrow = V + ((size_t)(b*8 + h)*64 + wave*16 + lr)*LKT;
        for (int pc = 0; pc < 2*NCH; ++pc) {
            short8 bf_ = *(const short8*)&vrow[pc*32 + g*8];
            #pragma unroll
            for (int mi = 0; mi < 2; ++mi) {
                short8 af = *(const short8*)&Ps[(mi*16 + lr)*LKP + pc*32 + g*8];
                o[mi] = __builtin_amdgcn_mfma_f32_16x16x32_bf16(af, bf_, o[mi], 0, 0, 0);
            }
        }
    } else {
        short* Vs = (short*)Ks;
        for (int pc = 0; pc < 2*NCH; ++pc) {
            __syncthreads();
            {
                int r = tid >> 3, c = (tid & 7) << 3;
                int kr = pc*32 + r;
                short8 v = {};
                if (kr < LK) v = *(const short8*)&V[(kvbase + kr)*ldv + h*64 + c];
                #pragma unroll
                for (int j = 0; j < 8; ++j) Vs[(c + j)*40 + r] = v[j];
            }
            __syncthreads();
            short8 bf_ = *(const short8*)&Vs[(wave*16 + lr)*40 + g*8];
            #pragma unroll
            for (int mi = 0; mi < 2; ++mi) {
                short8 af = *(const short8*)&Ps[(mi*16 + lr)*LKP + pc*32 + g*8];
                o[mi] = __builtin_amdgcn_mfma_f32_16x16x32_bf16(af, bf_, o[mi], 0, 0, 0);
            }
        }
    }
    const int cr4g = g * 4;
    #pragma unroll
    for (int mi = 0; mi < 2; ++mi)
        #pragma unroll
        for (int q = 0; q < 4; ++q) {
            int rl = mi*16 + cr4g + q;
            storef(&ctx[(qbase + rl)*512 + h*64 + wave*16 + lr], o[mi][q]);
        }
}

// ---------------- bulk f32 -> bf16 converter
struct CvtSeg { const float* src; bf16* dst; };
struct CvtArgs { CvtSeg seg[16]; int cum[17]; int nseg; };
__global__ void k_cvt(CvtArgs a)
{
    int gid = blockIdx.x*256 + threadIdx.x;
    if (gid >= a.cum[a.nseg]) return;
    int s = 0;
    while (s < a.nseg-1 && gid >= a.cum[s+1]) ++s;
    int off = (gid - a.cum[s]) * 8;
    short8 v; load8(a.seg[s].src + off, &v);
    *(short8*)(a.seg[s].dst + off) = v;
}

// ---------------- attr pad-convert
__global__ void k_cvt_pad(const float* __restrict__ a, const float* __restrict__ wk,
                          const float* __restrict__ wv, bf16* __restrict__ attrp,
                          bf16* __restrict__ kvwp)
{
    int t = blockIdx.x*256 + threadIdx.x;     // 1344*320
    if (t >= 1344*320) return;
    int r = t / 320, c = t % 320;
    float v = 0.0f;
    if (c < 300) {
        if (r < 320) v = a[(size_t)r*300 + c];
        else if (r < 832) v = wk[(size_t)(r-320)*300 + c];
        else v = wv[(size_t)(r-832)*300 + c];
    }
    if (r < 320) storef(&attrp[(size_t)r*320 + c], v);
    else storef(&kvwp[(size_t)(r-320)*320 + c], v);
}

__global__ void k_cat2(const float* __restrict__ a, const float* __restrict__ b,
                       float* __restrict__ dst)
{
    int t = blockIdx.x*256 + threadIdx.x;
    if (t < 512) dst[t] = a[t];
    else if (t < 1024) dst[t] = b[t-512];
}

__global__ void k_cat3(const float* __restrict__ a, const float* __restrict__ b,
                       const float* __restrict__ c, float* __restrict__ dst)
{
    int t = blockIdx.x*256 + threadIdx.x;
    if (t < 512) dst[t] = a[t];
    else if (t < 1024) dst[t] = b[t-512];
    else if (t < 1536) dst[t] = c[t-1024];
}

__global__ void k_zero(bf16* __restrict__ p, int n8)
{
    int t = blockIdx.x*256 + threadIdx.x;
    if (t < n8) { short8 z = {}; *(short8*)&p[t*8] = z; }
}

// ---------------- fused custom-LN + GLU -> bf16 [8192,256]
__global__ void k_lnglu(const float* __restrict__ x, const float* __restrict__ a,
                        const float* __restrict__ bpar, bf16* __restrict__ out)
{
    int r = blockIdx.x, tid = threadIdx.x;
    const float* xr = x + (size_t)r*512;
    float v0 = xr[tid], v1 = xr[tid+256];
    __shared__ float red[256];
    red[tid] = v0+v1; __syncthreads();
    for (int s=128;s>0;s>>=1){ if(tid<s) red[tid]+=red[tid+s]; __syncthreads(); }
    float mean = red[0]*(1.0f/512.0f); __syncthreads();
    float d0 = v0-mean, d1 = v1-mean;
    red[tid] = d0*d0+d1*d1; __syncthreads();
    for (int s=128;s>0;s>>=1){ if(tid<s) red[tid]+=red[tid+s]; __syncthreads(); }
    float stdv = sqrtf(red[0]*(1.0f/511.0f));
    float inv = 1.0f/(stdv + 1e-6f);
    float o0 = a[tid]    *d0*inv + bpar[tid];
    float o1 = a[tid+256]*d1*inv + bpar[tid+256];
    storef(&out[(size_t)r*256 + tid], o0 * sigm(o1));
}

// ---------------- LSTM steps t=0,1
__global__ void k_lstm_step(const bf16* __restrict__ XW, const bf16* __restrict__ G,
                            const float* __restrict__ bih, const float* __restrict__ bhh,
                            bf16* __restrict__ h, float* __restrict__ c, int t, int first)
{
    int idx = blockIdx.x*256 + threadIdx.x;
    int n = idx >> 9, j = idx & 511;
    int b = n >> 9, l = n & 511;
    int lp = l - 2 + t;
    float gi, gf, gg, go;
    if (lp >= 0) {
        const bf16* xr = XW + ((size_t)(b*512 + lp))*2048;
        gi = tof(xr[j]); gf = tof(xr[512+j]); gg = tof(xr[1024+j]); go = tof(xr[1536+j]);
    } else {
        gi = bih[j]; gf = bih[512+j]; gg = bih[1024+j]; go = bih[1536+j];
    }
    if (first) {
        gi += bhh[j]; gf += bhh[512+j]; gg += bhh[1024+j]; go += bhh[1536+j];
        float cn = sigm(gi)*tanhf(gg);
        c[idx] = cn;
        storef(&h[idx], sigm(go)*tanhf(cn));
    } else {
        const bf16* gr = G + (size_t)n*2048;
        gi += tof(gr[j]); gf += tof(gr[512+j]); gg += tof(gr[1024+j]); go += tof(gr[1536+j]);
        float cn = sigm(gf)*c[idx] + sigm(gi)*tanhf(gg);
        c[idx] = cn;
        storef(&h[idx], sigm(go)*tanhf(cn));
    }
}

// ---------------- LSTM final step t=2 fused with residual add: x1 = dec + h
__global__ void k_lstm_last(const bf16* __restrict__ XW, const bf16* __restrict__ G,
                            const float* __restrict__ dec, const float* __restrict__ c,
                            float* __restrict__ x1f, bf16* __restrict__ x1b)
{
    int idx = blockIdx.x*256 + threadIdx.x;
    int n = idx >> 9, j = idx & 511;
    int b = n >> 9, l = n & 511;
    const bf16* xr = XW + ((size_t)(b*512 + l))*2048;
    float gi = tof(xr[j]), gf = tof(xr[512+j]), gg = tof(xr[1024+j]), go = tof(xr[1536+j]);
    const bf16* gr = G + (size_t)n*2048;
    gi += tof(gr[j]); gf += tof(gr[512+j]); gg += tof(gr[1024+j]); go += tof(gr[1536+j]);
    float cn = sigm(gf)*c[idx] + sigm(gi)*tanhf(gg);
    float h = sigm(go)*tanhf(cn);
    float v = dec[idx] + h;
    x1f[idx] = v;
    storef(&x1b[idx], v);
}

template<typename RT>
__global__ void k_ln_res(const bf16* __restrict__ x, const RT* __restrict__ res,
                         float* __restrict__ out, bf16* __restrict__ outb, float eps)
{
    int r = blockIdx.x, tid = threadIdx.x;
    const bf16* xr = x + (size_t)r*512;
    const RT* rr = res + (size_t)r*512;
    float v0 = tof(xr[tid]) + tof(rr[tid]), v1 = tof(xr[tid+256]) + tof(rr[tid+256]);
    __shared__ float red[256];
    red[tid] = v0+v1; __syncthreads();
    for (int s=128;s>0;s>>=1){ if(tid<s) red[tid]+=red[tid+s]; __syncthreads(); }
    float mean = red[0]*(1.0f/512.0f); __syncthreads();
    float d0 = v0-mean, d1 = v1-mean;
    red[tid] = d0*d0+d1*d1; __syncthreads();
    for (int s=128;s>0;s>>=1){ if(tid<s) red[tid]+=red[tid+s]; __syncthreads(); }
    float inv = rsqrtf(red[0]*(1.0f/512.0f) + eps);
    float o0 = d0*inv, o1 = d1*inv;
    out[(size_t)r*512 + tid]     = o0;
    out[(size_t)r*512 + tid+256] = o1;
    if (outb) {
        storef(&outb[(size_t)r*512 + tid],     o0);
        storef(&outb[(size_t)r*512 + tid+256], o1);
    }
}

__global__ void k_gate_ln(const bf16* __restrict__ ctpre, const float* __restrict__ img,
                          const float* __restrict__ attr, const float* __restrict__ na,
                          const float* __restrict__ nb, bf16* __restrict__ out)
{
    int r = blockIdx.x, tid = threadIdx.x;
    size_t base = (size_t)r*512;
    float ct0 = sigm(tof(ctpre[base+tid]));
    float v0 = ct0*fmaxf(img[base+tid],0.f) + (1.f-ct0)*fmaxf(attr[base+tid],0.f);
    float ct1 = sigm(tof(ctpre[base+tid+256]));
    float v1 = ct1*fmaxf(img[base+tid+256],0.f) + (1.f-ct1)*fmaxf(attr[base+tid+256],0.f);
    __shared__ float red[256];
    red[tid] = v0+v1; __syncthreads();
    for (int s=128;s>0;s>>=1){ if(tid<s) red[tid]+=red[tid+s]; __syncthreads(); }
    float mean = red[0]*(1.0f/512.0f); __syncthreads();
    float d0 = v0-mean, d1 = v1-mean;
    red[tid] = d0*d0+d1*d1; __syncthreads();
    for (int s=128;s>0;s>>=1){ if(tid<s) red[tid]+=red[tid+s]; __syncthreads(); }
    float stdv = sqrtf(red[0]*(1.0f/511.0f));
    float inv = 1.0f/(stdv + 1e-6f);
    storef(&out[base+tid],     na[tid]    *d0*inv + nb[tid]);
    storef(&out[base+tid+256], na[tid+256]*d1*inv + nb[tid+256]);
}

__global__ void k_fold(const float* __restrict__ fcw, bf16* __restrict__ fold)
{
    int idx = blockIdx.x*256 + threadIdx.x;
    int d = idx >> 9, j = idx & 511;
    storef(&fold[idx], fcw[(size_t)d*1024 + j] + fcw[(size_t)d*1024 + 512 + j]);
}

extern "C" void kernel_launch(void* const* d_in, const int* in_sizes, int n_in,
                              void* d_out, int out_size, void* d_ws, size_t ws_size,
                              hipStream_t stream)
{
    const float* dec_inputs  = (const float*)d_in[0];
    const float* enc_outputs = (const float*)d_in[1];
    const float* attr_out    = (const float*)d_in[2];
    const float* rnn_a  = (const float*)d_in[6];
    const float* rnn_b  = (const float*)d_in[7];
    const float* conv_w = (const float*)d_in[8];
    const float* conv_b = (const float*)d_in[9];
    const float* w_ih   = (const float*)d_in[10];
    const float* w_hh   = (const float*)d_in[11];
    const float* b_ih   = (const float*)d_in[12];
    const float* b_hh   = (const float*)d_in[13];
    const float* sa_wq  = (const float*)d_in[14]; const float* sa_bq = (const float*)d_in[15];
    const float* sa_wk  = (const float*)d_in[16]; const float* sa_bk = (const float*)d_in[17];
    const float* sa_wv  = (const float*)d_in[18]; const float* sa_bv = (const float*)d_in[19];
    const float* sa_wo  = (const float*)d_in[20]; const float* sa_bo = (const float*)d_in[21];
    const float* ea_wq  = (const float*)d_in[22]; const float* ea_bq = (const float*)d_in[23];
    const float* ea_wk  = (const float*)d_in[24]; const float* ea_bk = (const float*)d_in[25];
    const float* ea_wv  = (const float*)d_in[26]; const float* ea_bv = (const float*)d_in[27];
    const float* ea_wo  = (const float*)d_in[28]; const float* ea_bo = (const float*)d_in[29];
    const float* aa_wq  = (const float*)d_in[30]; const float* aa_bq = (const float*)d_in[31];
    const float* aa_wk  = (const float*)d_in[32]; const float* aa_bk = (const float*)d_in[33];
    const float* aa_wv  = (const float*)d_in[34]; const float* aa_bv = (const float*)d_in[35];
    const float* aa_wo  = (const float*)d_in[36]; const float* aa_bo = (const float*)d_in[37];
    const float* fc_w   = (const float*)d_in[38]; const float* fc_b  = (const float*)d_in[39];
    const float* norm_a = (const float*)d_in[40]; const float* norm_b= (const float*)d_in[41];
    const float* ffn_w1 = (const float*)d_in[42]; const float* ffn_b1= (const float*)d_in[43];
    const float* ffn_w2 = (const float*)d_in[44]; const float* ffn_b2= (const float*)d_in[45];

    float* out_y  = (float*)d_out;
    float* out_sa = out_y + 4194304ull;      // [16,8,512,512] f32
    float* out_ea = out_sa + 33554432ull;    // [16,8,512,196] f32

    // scratch inside out_sa (dead until k_attn<self> writes it)
    bf16* xwb = (bf16*)out_sa;                    // [8192,2048]
    bf16* gb  = xwb + 16777216ull;
    bf16* wA  = (bf16*)(out_sa + 16777216ull);
    bf16* conv_wb = wA;
    bf16* w_ihb   = conv_wb + 131072;
    bf16* w_hhb   = w_ihb + 1048576;
    bf16* sa_wqb  = w_hhb + 1048576;              // wq|wk|wv adjacent (fused QKV)
    bf16* sa_wkb  = sa_wqb + 262144;
    bf16* sa_wvb  = sa_wkb + 262144;
    // scratch inside out_ea (dead until k_attn<enc> writes it)
    bf16* enc_b   = (bf16*)out_ea;                // [3136,4096]
    bf16* ea_wkb  = (bf16*)(out_ea + 6422528ull); // wk|wv adjacent (fused KV)
    bf16* ea_wvb  = ea_wkb + 2097152;

    char* W = (char*)d_ws;
    float* S0 = (float*)(W);                      // x1 / attr ; aliases (dead phases)
    float* S1 = (float*)(W + (16ull<<20));        // dec_out ; midb in E
    float* S2 = (float*)(W + (32ull<<20));        // c / img
    bf16*  T0 = (bf16*) (W + (48ull<<20));        // fat q|k [8192,1024] spans T0..T1 / ctpre
    bf16*  T1 = (bf16*) (W + (56ull<<20));        // proj out / ffn2out
    bf16*  T2 = (bf16*) (W + (64ull<<20));        // vt_self / proj out / y1
    bf16*  T3 = (bf16*) (W + (72ull<<20));        // ctx
    bf16*  glufb = (bf16*)(W + (80ull<<20));
    bf16*  hb    = (bf16*)(W + (80ull<<20));      // h / x1b
    bf16*  dec_out_b = (bf16*)(W + (88ull<<20));
    bf16*  img_b     = (bf16*)(W + (96ull<<20));
    bf16*  wsW   = (bf16*)(W + (104ull<<20));
    bf16* ea_wqb = wsW;                           // ea_wq|aa_wq adjacent
    bf16* aa_wqb = ea_wqb + 262144;
    bf16* ea_wob = aa_wqb + 262144;
    bf16* aa_wob = ea_wob + 262144;
    bf16* sa_wob = aa_wob + 262144;
    bf16* foldb  = sa_wob + 262144;
    bf16* ffn_w1b = foldb + 262144;
    bf16* ffn_w2b = ffn_w1b + 1048576;
    float* b_qkv    = (float*)(W + (112ull<<20)); // [1536] sa_bq|sa_bk|sa_bv
    float* bq_eaaa  = b_qkv + 1536;               // [1024] ea_bq|aa_bq
    float* b_attrkv = bq_eaaa + 1024;             // [1024] aa_bk|aa_bv
    float* b_enckv  = b_attrkv + 1024;            // [1024] ea_bk|ea_bv
    bf16* midb = (bf16*)S1;                       // [8192,2048] phase E
    // aliases inside dead x1 region (valid after phase B):
    bf16* kenc   = (bf16*)S0;                     // [3136,512]   phase C
    bf16* vt_enc = (bf16*)(W + (4ull<<20));       // [8192,256]   phase C (V^T, zero-padded)
    bf16* kvattr = (bf16*)(W + (8ull<<20));       // [320,1024] = K|V attr, phase D
    bf16* attrp  = (bf16*)(W + (10ull<<20));      // [320,320]  padded attr_out
    bf16* kvwp   = (bf16*)(W + (11ull<<20));      // [1024,320] padded aa_wk|aa_wv

    // ---- Phase 0 ----
    {
        CvtArgs ca;
        const float* srcs[16] = {conv_w, w_ih, w_hh, sa_wq, sa_wk, sa_wv, sa_wo, ea_wq,
                                 aa_wq, ea_wo, aa_wo, ffn_w1, ffn_w2, ea_wk, ea_wv, enc_outputs};
        bf16* dsts[16] = {conv_wb, w_ihb, w_hhb, sa_wqb, sa_wkb, sa_wvb, sa_wob, ea_wqb,
                          aa_wqb, ea_wob, aa_wob, ffn_w1b, ffn_w2b, ea_wkb, ea_wvb, enc_b};
        int ns[16] = {131072, 1048576, 1048576, 262144, 262144, 262144, 262144, 262144,
                      262144, 262144, 262144, 1048576, 1048576, 2097152, 2097152, 12845056};
        int cum = 0;
        for (int i = 0; i < 16; ++i) { ca.seg[i] = {srcs[i], dsts[i]}; ca.cum[i] = cum; cum += ns[i]/8; }
        ca.cum[16] = cum; ca.nseg = 16;
        k_cvt<<<(cum + 255)/256, 256, 0, stream>>>(ca);
    }
    k_fold<<<1024,256,0,stream>>>(fc_w, foldb);
    k_cat3<<<6,256,0,stream>>>(sa_bq, sa_bk, sa_bv, b_qkv);
    k_cat2<<<4,256,0,stream>>>(ea_bq, aa_bq, bq_eaaa);
    k_cat2<<<4,256,0,stream>>>(aa_bk, aa_bv, b_attrkv);
    k_cat2<<<4,256,0,stream>>>(ea_bk, ea_bv, b_enckv);

    // gP64: 64x64 tiles for N=512 projection GEMMs -> 1024 blocks = 4/CU (was 2/CU)
    dim3 gP(4,128), gP64(8,128), gPQ(8,128), gQKV(12,128), gX(16,64), gEKV(8,49), gA(16,128);

    // ---- Phase A: LocalRNN ----
    k_lnglu<<<8192,256,0,stream>>>(dec_inputs, rnn_a, rnn_b, glufb);
    k_gemm_fast<64,64,bf16,false><<<gP64,256,0,stream>>>(glufb,256, conv_wb,256, T0,512, nullptr, conv_b, 256);
    k_gemm_fast<128,128,bf16,false><<<gX,256,0,stream>>>(T0,512, w_ihb,512, xwb,2048, nullptr, b_ih, 512);
    k_lstm_step<<<16384,256,0,stream>>>(xwb, nullptr, b_ih, b_hh, hb, S2, 0, 1);
    k_gemm_fast<128,128,bf16,false><<<gX,256,0,stream>>>(hb,512, w_hhb,512, gb,2048, nullptr, b_hh, 512);
    k_lstm_step<<<16384,256,0,stream>>>(xwb, gb, b_ih, b_hh, hb, S2, 1, 0);
    k_gemm_fast<128,128,bf16,false><<<gX,256,0,stream>>>(hb,512, w_hhb,512, gb,2048, nullptr, b_hh, 512);
    k_lstm_last<<<16384,256,0,stream>>>(xwb, gb, dec_inputs, S2, S0, hb);      // x1 f32->S0, bf16->hb

    // ---- Phase B: causal self-attention ----
    k_gemm_fast<64,128,bf16,false,512,512,1024><<<gQKV,256,0,stream>>>(
        hb,512, sa_wqb,512, T0,1024, T2, b_qkv, 512);                          // Q|K normal, V^T->T2
    k_attn<512,512,true,true,true><<<gA,256,0,stream>>>(T0,1024, T0+512,1024, T2,0, out_sa, T3);
    k_gemm_fast<64,64,bf16,false><<<gP64,256,0,stream>>>(T3,512, sa_wob,512, T1,512, nullptr, sa_bo, 512);
    k_ln_res<float><<<8192,256,0,stream>>>(T1, S0, S1, dec_out_b, 1e-5f);

    // ---- Phase C: enc cross-attention ----
    k_zero<<<1024,256,0,stream>>>(vt_enc, 262144);
    k_gemm_fast<64,128,bf16,false><<<gPQ,256,0,stream>>>(dec_out_b,512, ea_wqb,512, T0,1024, nullptr, bq_eaaa, 512);
    k_gemm_fast<64,128,bf16,false,196,256,512><<<gEKV,256,0,stream>>>(
        enc_b,4096, ea_wkb,4096, kenc,512, vt_enc, b_enckv, 4096);             // K normal, V^T->vt_enc
    k_attn<196,256,false,true,true><<<gA,256,0,stream>>>(T0,1024, kenc,512, vt_enc,0, out_ea, T3);
    k_gemm_fast<64,64,bf16,false><<<gP64,256,0,stream>>>(T3,512, ea_wob,512, T2,512, nullptr, ea_bo, 512);
    k_ln_res<float><<<8192,256,0,stream>>>(T2, S1, S2, img_b, 1e-5f);

    // ---- Phase D: attr cross-attention ----
    k_cvt_pad<<<1680,256,0,stream>>>(attr_out, aa_wk, aa_wv, attrp, kvwp);
    { dim3 ga(8,5,1);
      k_gemm_fast<64,128,bf16,false><<<ga,256,0,stream>>>(attrp,320, kvwp,320, kvattr,1024, nullptr, b_attrkv, 320); }
    k_attn<20,20,false,false,false><<<gA,256,0,stream>>>(T0+512,1024, kvattr,1024, kvattr+512,1024, nullptr, T3);
    k_gemm_fast<64,64,bf16,false><<<gP64,256,0,stream>>>(T3,512, aa_wob,512, T2,512, nullptr, aa_bo, 512);
    k_ln_res<float><<<8192,256,0,stream>>>(T2, S1, S0, nullptr, 1e-5f);

    // ---- Phase E: gated fusion + FFN ----
    k_gemm_fast<64,64,bf16,false><<<gP64,256,0,stream>>>(img_b,512, foldb,512, T0,512, nullptr, fc_b, 512);
    k_gate_ln<<<8192,256,0,stream>>>(T0, S2, S0, norm_a, norm_b, T2);
    k_gemm_fast<128,128,bf16,true><<<gX,256,0,stream>>>(T2,512, ffn_w1b,512, midb,2048, nullptr, ffn_b1, 512);
    k_gemm_fast<64,128,bf16,false><<<gP,256,0,stream>>>(midb,2048, ffn_w2b,2048, T1,512, nullptr, ffn_b2, 2048);
    k_ln_res<bf16><<<8192,256,0,stream>>>(T1, T2, out_y, nullptr, 1e-5f);
}